// Round 16
// baseline (1055.290 us; speedup 1.0000x reference)
//
#include <hip/hip_runtime.h>
#include <math.h>

#define Nn 50000
#define Ee 1600000
#define Bb 512
#define TE 64
#define NTILES (Ee / TE)
#define NB ((Nn + 255) / 256)

typedef __bf16 bf16;
typedef __bf16 bf16x8 __attribute__((ext_vector_type(8)));
typedef __bf16 bf16x4 __attribute__((ext_vector_type(4)));
typedef float f32x4 __attribute__((ext_vector_type(4)));

__device__ __forceinline__ float silu_f(float v) {
    return v * __builtin_amdgcn_rcpf(1.f + __expf(-v));
}
__device__ __forceinline__ float tanh_f(float x) {
    float e = __expf(2.f * x);
    return 1.f - 2.f * __builtin_amdgcn_rcpf(e + 1.f);
}
__device__ __forceinline__ int pack2bf(float a, float b) {
    unsigned short ua = __builtin_bit_cast(unsigned short, (bf16)a);
    unsigned short ub = __builtin_bit_cast(unsigned short, (bf16)b);
    return (int)ua | ((int)ub << 16);
}
__device__ __forceinline__ float unlo(int v) {
    return __builtin_bit_cast(float, v << 16);
}
__device__ __forceinline__ float unhi(int v) {
    return __builtin_bit_cast(float, v & 0xffff0000);
}

// ---------------- init: h = emb[z] (fp32 + bf16 mirror) ----------------
__global__ void k_init_h(float* __restrict__ h, bf16* __restrict__ hb,
                         const int* __restrict__ z, const float* __restrict__ emb) {
    int i = blockIdx.x * blockDim.x + threadIdx.x;
    if (i < Nn * 64) {
        int n = i >> 6, f = i & 63;
        float v = emb[z[n] * 64 + f];
        h[i] = v;
        hb[i] = (bf16)v;
    }
}

// ---------------- weight packing into MFMA A-fragment order ----------------
__device__ __forceinline__ void packfrag(bf16* dst, const float* src, int idx) {
    int j = idx & 7, lane = (idx >> 3) & 63, gT = idx >> 9;
    int kc = gT >> 2, T = gT & 3;
    int k = kc * 32 + (lane >> 4) * 8 + j;
    int n = T * 16 + (lane & 15);
    dst[idx] = (bf16)src[k * 64 + n];
}

__global__ void k_pack(const float* __restrict__ eW1, const float* __restrict__ eW2,
                       const float* __restrict__ nW1, const float* __restrict__ nW2,
                       const float* __restrict__ qW1,
                       bf16* __restrict__ pw1, bf16* __restrict__ pw2,
                       bf16* __restrict__ pn1, bf16* __restrict__ pn2,
                       bf16* __restrict__ pq1) {
    int tid = blockIdx.x * blockDim.x + threadIdx.x;
    if (tid < 32768) {
        int l = tid >> 13, idx = tid & 8191;
        packfrag(pw1 + l * 8192, eW1 + (size_t)l * 129 * 64, idx);
    } else if (tid < 49152) {
        int i = tid - 32768, l = i >> 12, idx = i & 4095;
        packfrag(pw2 + l * 4096, eW2 + (size_t)l * 4096, idx);
    } else if (tid < 81920) {
        int i = tid - 49152, l = i >> 13, idx = i & 8191;
        packfrag(pn1 + l * 8192, nW1 + (size_t)l * 8192, idx);
    } else if (tid < 98304) {
        int i = tid - 81920, l = i >> 12, idx = i & 4095;
        packfrag(pn2 + l * 4096, nW2 + (size_t)l * 4096, idx);
    } else if (tid < 102400) {
        packfrag(pq1, qW1, tid - 98304);
    }
}

// ---------------- CSR build ----------------
__global__ void k_hist(const int* __restrict__ rows, int* __restrict__ deg) {
    int e = blockIdx.x * blockDim.x + threadIdx.x;
    if (e < Ee) atomicAdd(&deg[rows[e]], 1);
}

__global__ void k_scan1(const int* __restrict__ deg, int* __restrict__ bsum) {
    __shared__ int red[4];
    int b = blockIdx.x;
    int i = b * 256 + threadIdx.x;
    int v = (i < Nn) ? deg[i] : 0;
#pragma unroll
    for (int off = 1; off < 64; off <<= 1) v += __shfl_xor(v, off);
    if ((threadIdx.x & 63) == 0) red[threadIdx.x >> 6] = v;
    __syncthreads();
    if (threadIdx.x == 0) bsum[b] = red[0] + red[1] + red[2] + red[3];
}

__global__ void k_scan2(const int* __restrict__ bsum, int* __restrict__ boff) {
    __shared__ int s[256];
    int t = threadIdx.x;
    int v = (t < NB) ? bsum[t] : 0;
    s[t] = v;
    __syncthreads();
    for (int off = 1; off < 256; off <<= 1) {
        int u = (t >= off) ? s[t - off] : 0;
        __syncthreads();
        s[t] += u;
        __syncthreads();
    }
    if (t < NB) boff[t] = s[t] - v;
}

__global__ void k_scan3(const int* __restrict__ deg, const int* __restrict__ boff,
                        int* __restrict__ rp) {
    __shared__ int s[256];
    int b = blockIdx.x, t = threadIdx.x;
    int i = b * 256 + t;
    int v = (i < Nn) ? deg[i] : 0;
    s[t] = v;
    __syncthreads();
    for (int off = 1; off < 256; off <<= 1) {
        int u = (t >= off) ? s[t - off] : 0;
        __syncthreads();
        s[t] += u;
        __syncthreads();
    }
    if (i < Nn) rp[i] = boff[b] + s[t] - v;
    if (i == Nn - 1) rp[Nn] = boff[b] + s[t];
}

// cols-only scatter; cur preloaded with rp so atomic returns absolute offset
__global__ void k_scatter(const int* __restrict__ rows, const int* __restrict__ cols,
                          int* __restrict__ cur, int* __restrict__ cols_s) {
    int e = blockIdx.x * blockDim.x + threadIdx.x;
    if (e < Ee) {
        int o = atomicAdd(&cur[rows[e]], 1);
        cols_s[o] = cols[e];
    }
}

// rows_s expansion from rp (deterministic, sequential writes)
__global__ void k_fillrows(const int* __restrict__ rp, int* __restrict__ rows_s) {
    int n = blockIdx.x * blockDim.x + threadIdx.x;
    if (n < Nn) {
        int st = rp[n], en = rp[n + 1];
        for (int o = st; o < en; ++o) rows_s[o] = n;
    }
}

// ---------------- per-layer node projection: Pa = H@W1a + b1, Pb = H@W1b (bf16 out) ----------------
__global__ __launch_bounds__(256) void k_proj(
    const bf16* __restrict__ hbuf, const bf16* __restrict__ pw1l,
    const float* __restrict__ b1v,
    bf16* __restrict__ Pa, bf16* __restrict__ Pb) {
    __shared__ __align__(16) bf16 inB[8 * 64 * 8];   // h B-frags
    __shared__ float dhT[64 * 65];
    __shared__ __align__(16) float sb1[64];

    const int t = threadIdx.x;
    const int l = t & 63, w = t >> 6, q = l >> 4, nl = l & 15;
    const int fq = 4 * q;
    const int ge = t >> 2, part = t & 3;

    bf16x8 w1f[4][4];
#pragma unroll
    for (int kc = 0; kc < 4; ++kc)
#pragma unroll
        for (int T = 0; T < 4; ++T)
            w1f[kc][T] = *(const bf16x8*)(pw1l + (((kc * 4 + T) * 64 + l) << 3));
    if (t < 64) sb1[t] = b1v[t];

    const int NT = (Nn + 63) / 64;
    for (int bt = blockIdx.x; bt < NT; bt += gridDim.x) {
        const int base = bt * 64;
        __syncthreads();  // protect inB/dhT reuse
        {
            int n = base + ge;
            if (n < Nn) {
                const bf16* hr = hbuf + ((size_t)n << 6) + part * 16;
                *(bf16x8*)&inB[(((part * 2 + 0) * 64) + ge) << 3] = *(const bf16x8*)(hr);
                *(bf16x8*)&inB[(((part * 2 + 1) * 64) + ge) << 3] = *(const bf16x8*)(hr + 8);
            } else {
                bf16x8 zz = {(bf16)0.f, (bf16)0.f, (bf16)0.f, (bf16)0.f,
                             (bf16)0.f, (bf16)0.f, (bf16)0.f, (bf16)0.f};
                *(bf16x8*)&inB[(((part * 2 + 0) * 64) + ge) << 3] = zz;
                *(bf16x8*)&inB[(((part * 2 + 1) * 64) + ge) << 3] = zz;
            }
        }
        __syncthreads();

        f32x4 apa[4], apb[4];
#pragma unroll
        for (int T = 0; T < 4; ++T) {
            apa[T] = (f32x4){0.f, 0.f, 0.f, 0.f};
            apb[T] = (f32x4){0.f, 0.f, 0.f, 0.f};
        }
#pragma unroll
        for (int kc = 0; kc < 2; ++kc) {
            bf16x8 bfrag = *(const bf16x8*)&inB[(((kc * 4 + q) * 64) + w * 16 + nl) << 3];
#pragma unroll
            for (int T = 0; T < 4; ++T) {
                apa[T] = __builtin_amdgcn_mfma_f32_16x16x32_bf16(w1f[kc][T], bfrag, apa[T], 0, 0, 0);
                apb[T] = __builtin_amdgcn_mfma_f32_16x16x32_bf16(w1f[kc + 2][T], bfrag, apb[T], 0, 0, 0);
            }
        }
        // write Pa (+bias) via LDS transpose, bf16 store
#pragma unroll
        for (int T = 0; T < 4; ++T) {
#pragma unroll
            for (int r = 0; r < 4; ++r)
                dhT[(T * 16 + fq + r) * 65 + w * 16 + nl] = apa[T][r] + sb1[T * 16 + fq + r];
        }
        __syncthreads();
        {
            int n = base + ge;
            if (n < Nn) {
#pragma unroll
                for (int j = 0; j < 4; ++j) {
                    int f = part * 16 + j * 4;
                    bf16x4 bv = {(bf16)dhT[(f + 0) * 65 + ge], (bf16)dhT[(f + 1) * 65 + ge],
                                 (bf16)dhT[(f + 2) * 65 + ge], (bf16)dhT[(f + 3) * 65 + ge]};
                    *(bf16x4*)(Pa + ((size_t)n << 6) + f) = bv;
                }
            }
        }
        __syncthreads();
        // write Pb via LDS transpose, bf16 store
#pragma unroll
        for (int T = 0; T < 4; ++T) {
#pragma unroll
            for (int r = 0; r < 4; ++r)
                dhT[(T * 16 + fq + r) * 65 + w * 16 + nl] = apb[T][r];
        }
        __syncthreads();
        {
            int n = base + ge;
            if (n < Nn) {
#pragma unroll
                for (int j = 0; j < 4; ++j) {
                    int f = part * 16 + j * 4;
                    bf16x4 bv = {(bf16)dhT[(f + 0) * 65 + ge], (bf16)dhT[(f + 1) * 65 + ge],
                                 (bf16)dhT[(f + 2) * 65 + ge], (bf16)dhT[(f + 3) * 65 + ge]};
                    *(bf16x4*)(Pb + ((size_t)n << 6) + f) = bv;
                }
            }
        }
    }
}

// ---------------- edge kernel: gather bf16 Pa/Pb + rank-1 + silu -> GEMM2 only ----------------
__global__ __launch_bounds__(256, 8) void k_edge(
    const int* __restrict__ rows_s, const int* __restrict__ cols_s,
    const bf16* __restrict__ Pa, const bf16* __restrict__ Pb,
    const float* __restrict__ x,
    const bf16* __restrict__ pw2l,
    const float* __restrict__ w1f32,
    const float* __restrict__ b2v,
    const float* __restrict__ cwv, const float* __restrict__ cbv,
    float* __restrict__ m_agg, float* __restrict__ x_acc) {
    __shared__ __align__(16) bf16 lw2[4096];   // 8 KB GEMM2 A-frags
    __shared__ __align__(16) float w128s[64], b2s[64], cws[64];
    __shared__ int mEp[32 * 65];               // packed bf16x2 [featpair][edge]
    __shared__ __align__(16) float relsm[64 * 4];
    __shared__ float coefs[64];
    __shared__ int srow[64];

    const int t = threadIdx.x;
    const int l = t & 63, w = t >> 6, q = l >> 4, nl = l & 15;
    const int fq = 4 * q;
    const int ge = l >> 2, part = l & 3;   // gather roles within wave

    // stage GEMM2 weights + tables into LDS (once)
    {
        const int4* s2 = (const int4*)pw2l;
        int4* d2p = (int4*)lw2;
#pragma unroll
        for (int i = 0; i < 2; ++i) d2p[t + 256 * i] = s2[t + 256 * i];
        if (t < 64) {
            w128s[t] = w1f32[128 * 64 + t];
            b2s[t] = b2v[t];
            cws[t] = cwv[t];
        }
    }
    const float cb0 = cbv[0];
    __syncthreads();

    for (int tile = blockIdx.x; tile < NTILES; tile += gridDim.x) {
        const int eo = tile * TE + w * 16;

        const int r_g = rows_s[eo + ge], c_g = cols_s[eo + ge];
        // geometry (redundant across the 4 lanes of an edge; broadcast loads)
        float rx = x[r_g * 3 + 0] - x[c_g * 3 + 0];
        float ry = x[r_g * 3 + 1] - x[c_g * 3 + 1];
        float rz = x[r_g * 3 + 2] - x[c_g * 3 + 2];
        float d2 = fmaf(rx, rx, fmaf(ry, ry, rz * rz));
        if (part == 0) {
            srow[w * 16 + ge] = r_g;
            float4 rv;
            rv.x = rx; rv.y = ry; rv.z = rz; rv.w = d2;
            *(float4*)&relsm[(w * 16 + ge) * 4] = rv;
        }

        // gather bf16 Pa[row], Pb[col]: lane (ge,part) takes feats part*16..+15 (32B/lane)
        const bf16* par = Pa + ((size_t)r_g << 6) + part * 16;
        const bf16* pbc = Pb + ((size_t)c_g << 6) + part * 16;
        int4 Ai = *(const int4*)(par);       // feat pairs 0..3
        int4 Aj = *(const int4*)(par + 8);   // feat pairs 4..7
        int4 Bi = *(const int4*)(pbc);
        int4 Bj = *(const int4*)(pbc + 8);
        const float4 w0 = *(const float4*)&w128s[part * 16 + 0];
        const float4 w1 = *(const float4*)&w128s[part * 16 + 4];
        const float4 w2q = *(const float4*)&w128s[part * 16 + 8];
        const float4 w3 = *(const float4*)&w128s[part * 16 + 12];

        // pre-activation + silu -> packed bf16 pairs (gather layout)
        int pk[8];
        pk[0] = pack2bf(silu_f(fmaf(w0.x, d2, unlo(Ai.x) + unlo(Bi.x))),
                        silu_f(fmaf(w0.y, d2, unhi(Ai.x) + unhi(Bi.x))));
        pk[1] = pack2bf(silu_f(fmaf(w0.z, d2, unlo(Ai.y) + unlo(Bi.y))),
                        silu_f(fmaf(w0.w, d2, unhi(Ai.y) + unhi(Bi.y))));
        pk[2] = pack2bf(silu_f(fmaf(w1.x, d2, unlo(Ai.z) + unlo(Bi.z))),
                        silu_f(fmaf(w1.y, d2, unhi(Ai.z) + unhi(Bi.z))));
        pk[3] = pack2bf(silu_f(fmaf(w1.z, d2, unlo(Ai.w) + unlo(Bi.w))),
                        silu_f(fmaf(w1.w, d2, unhi(Ai.w) + unhi(Bi.w))));
        pk[4] = pack2bf(silu_f(fmaf(w2q.x, d2, unlo(Aj.x) + unlo(Bj.x))),
                        silu_f(fmaf(w2q.y, d2, unhi(Aj.x) + unhi(Bj.x))));
        pk[5] = pack2bf(silu_f(fmaf(w2q.z, d2, unlo(Aj.y) + unlo(Bj.y))),
                        silu_f(fmaf(w2q.w, d2, unhi(Aj.y) + unhi(Bj.y))));
        pk[6] = pack2bf(silu_f(fmaf(w3.x, d2, unlo(Aj.z) + unlo(Bj.z))),
                        silu_f(fmaf(w3.y, d2, unhi(Aj.z) + unhi(Bj.z))));
        pk[7] = pack2bf(silu_f(fmaf(w3.z, d2, unlo(Aj.w) + unlo(Bj.w))),
                        silu_f(fmaf(w3.w, d2, unhi(Aj.w) + unhi(Bj.w))));

        // GEMM2: shuffle-transpose (gather layout -> B-frag layout) + 8 MFMAs
        f32x4 a2[4];
#pragma unroll
        for (int T = 0; T < 4; ++T) a2[T] = (f32x4){0.f, 0.f, 0.f, 0.f};
#pragma unroll
        for (int c2 = 0; c2 < 2; ++c2) {
            union { int i[4]; bf16x8 v; } bu;
            int src = nl * 4 + 2 * c2 + (q >> 1);
#pragma unroll
            for (int d = 0; d < 4; ++d) {
                int t0 = __shfl(pk[d], src);
                int t1 = __shfl(pk[4 + d], src);
                bu.i[d] = (q & 1) ? t1 : t0;
            }
#pragma unroll
            for (int T = 0; T < 4; ++T) {
                bf16x8 wf = *(const bf16x8*)&lw2[(((c2 * 4 + T) * 64) + l) << 3];
                a2[T] = __builtin_amdgcn_mfma_f32_16x16x32_bf16(wf, bu.v, a2[T], 0, 0, 0);
            }
        }
        // epilogue2: bias + silu -> packed mE; coef dot in fp32 (pre-pack values)
        float pc = 0.f;
#pragma unroll
        for (int T = 0; T < 4; ++T) {
            const float4 bq = *(const float4*)&b2s[T * 16 + fq];
            const float4 cq = *(const float4*)&cws[T * 16 + fq];
            float m0 = silu_f(a2[T][0] + bq.x);
            float m1 = silu_f(a2[T][1] + bq.y);
            float m2 = silu_f(a2[T][2] + bq.z);
            float m3 = silu_f(a2[T][3] + bq.w);
            int p0 = (T * 16 + fq) >> 1;
            mEp[(p0 + 0) * 65 + w * 16 + nl] = pack2bf(m0, m1);
            mEp[(p0 + 1) * 65 + w * 16 + nl] = pack2bf(m2, m3);
            pc += m0 * cq.x + m1 * cq.y + m2 * cq.z + m3 * cq.w;
        }
        pc += __shfl_xor(pc, 16);
        pc += __shfl_xor(pc, 32);
        if (q == 0) coefs[w * 16 + nl] = tanh_f(pc + cb0);
        __syncthreads();  // barrier A: mEp/relsm/srow/coefs complete

        // segment detection (redundant per wave) + block-partitioned aggregation
        {
            int rl = srow[l];
            int rprev = __shfl(rl, l - 1);
            bool isst = (l == 0) || (rl != rprev);
            unsigned long long mask = __ballot(isst);
            const int pair = l & 31, half = l >> 5;
            unsigned long long mm = mask;
            int s = 0;
            while (mm) {
                int st = __ffsll(mm) - 1;
                mm &= mm - 1;
                if ((s & 3) == w) {
                    int en = mm ? (__ffsll(mm) - 1) : TE;
                    int row = __shfl(rl, st);
                    float s0 = 0.f, s1 = 0.f, sx = 0.f;
                    for (int e = st + half; e < en; e += 2) {
                        int pv = mEp[pair * 65 + e];
                        s0 += __builtin_bit_cast(float, pv << 16);
                        s1 += __builtin_bit_cast(float, pv & 0xffff0000);
                    }
                    if (half == 1 && pair < 3) {
                        for (int e = st; e < en; ++e)
                            sx += relsm[e * 4 + pair] * coefs[e];
                    }
                    s0 += __shfl_xor(s0, 32);
                    s1 += __shfl_xor(s1, 32);
                    if (half == 0) {
                        atomicAdd(m_agg + (size_t)row * 64 + 2 * pair, s0);
                        atomicAdd(m_agg + (size_t)row * 64 + 2 * pair + 1, s1);
                    } else if (pair < 3) {
                        atomicAdd(x_acc + (size_t)row * 3 + pair, sx);
                    }
                }
                s++;
            }
        }
        __syncthreads();  // barrier B: aggregation done before LDS reuse
    }
}

// ---------------- node kernel (MFMA, grid-stride, weights hoisted) ----------------
__global__ __launch_bounds__(256) void k_node(
    const float* __restrict__ m_agg, const float* __restrict__ x_acc,
    const bf16* __restrict__ pn1l, const bf16* __restrict__ pn2l,
    const float* __restrict__ b1v, const float* __restrict__ b2v,
    float* __restrict__ h, bf16* __restrict__ hbuf, float* __restrict__ x) {
    __shared__ __align__(16) bf16 inB[16 * 64 * 8];
    __shared__ float dhT[64 * 65];
    __shared__ __align__(16) float sb1[64], sb2[64];

    const int t = threadIdx.x;
    const int l = t & 63, w = t >> 6, q = l >> 4, nl = l & 15;
    const int qh = q >> 1, qb = 2 * (q & 1), fq = 4 * q;
    const int ge = t >> 2, part = t & 3;

    bf16x8 w1f[4][4];
#pragma unroll
    for (int kc = 0; kc < 4; ++kc)
#pragma unroll
        for (int T = 0; T < 4; ++T)
            w1f[kc][T] = *(const bf16x8*)(pn1l + (((kc * 4 + T) * 64 + l) << 3));
    bf16x8 w2f[2][4];
#pragma unroll
    for (int c = 0; c < 2; ++c)
#pragma unroll
        for (int T = 0; T < 4; ++T)
            w2f[c][T] = *(const bf16x8*)(pn2l + (((c * 4 + T) * 64 + l) << 3));
    if (t < 64) { sb1[t] = b1v[t]; sb2[t] = b2v[t]; }

    const int NT = (Nn + 63) / 64;
    for (int bt = blockIdx.x; bt < NT; bt += gridDim.x) {
        const int base = bt * 64;
        __syncthreads();  // protect inB reuse across iterations
        {
            int n = base + ge;
            if (n < Nn) {
                const bf16* hr = hbuf + ((size_t)n << 6) + part * 16;
                *(bf16x8*)&inB[(((part * 2 + 0) * 64) + ge) << 3] = *(const bf16x8*)(hr);
                *(bf16x8*)&inB[(((part * 2 + 1) * 64) + ge) << 3] = *(const bf16x8*)(hr + 8);
                const float* mr = m_agg + ((size_t)n << 6) + part * 16;
                float4 m0 = *(const float4*)(mr + 0);
                float4 m1 = *(const float4*)(mr + 4);
                float4 m2 = *(const float4*)(mr + 8);
                float4 m3 = *(const float4*)(mr + 12);
                bf16x8 bm0 = {(bf16)m0.x, (bf16)m0.y, (bf16)m0.z, (bf16)m0.w,
                              (bf16)m1.x, (bf16)m1.y, (bf16)m1.z, (bf16)m1.w};
                bf16x8 bm1 = {(bf16)m2.x, (bf16)m2.y, (bf16)m2.z, (bf16)m2.w,
                              (bf16)m3.x, (bf16)m3.y, (bf16)m3.z, (bf16)m3.w};
                *(bf16x8*)&inB[(((8 + part * 2 + 0) * 64) + ge) << 3] = bm0;
                *(bf16x8*)&inB[(((8 + part * 2 + 1) * 64) + ge) << 3] = bm1;
            } else {
                bf16x8 zz = {(bf16)0.f, (bf16)0.f, (bf16)0.f, (bf16)0.f,
                             (bf16)0.f, (bf16)0.f, (bf16)0.f, (bf16)0.f};
                *(bf16x8*)&inB[(((part * 2 + 0) * 64) + ge) << 3] = zz;
                *(bf16x8*)&inB[(((part * 2 + 1) * 64) + ge) << 3] = zz;
                *(bf16x8*)&inB[(((8 + part * 2 + 0) * 64) + ge) << 3] = zz;
                *(bf16x8*)&inB[(((8 + part * 2 + 1) * 64) + ge) << 3] = zz;
            }
        }
        __syncthreads();

        f32x4 a1[4];
#pragma unroll
        for (int T = 0; T < 4; ++T) a1[T] = (f32x4){0.f, 0.f, 0.f, 0.f};
#pragma unroll
        for (int kc = 0; kc < 4; ++kc) {
            bf16x8 bfrag = *(const bf16x8*)&inB[(((kc * 4 + q) * 64) + w * 16 + nl) << 3];
#pragma unroll
            for (int T = 0; T < 4; ++T)
                a1[T] = __builtin_amdgcn_mfma_f32_16x16x32_bf16(w1f[kc][T], bfrag, a1[T], 0, 0, 0);
        }
        int pk[4][2];
#pragma unroll
        for (int T = 0; T < 4; ++T) {
            const float4 bq = *(const float4*)&sb1[T * 16 + fq];
            float h0 = silu_f(a1[T][0] + bq.x);
            float h1 = silu_f(a1[T][1] + bq.y);
            float h2 = silu_f(a1[T][2] + bq.z);
            float h3 = silu_f(a1[T][3] + bq.w);
            pk[T][0] = pack2bf(h0, h1);
            pk[T][1] = pack2bf(h2, h3);
        }
        f32x4 a2[4];
#pragma unroll
        for (int T = 0; T < 4; ++T) a2[T] = (f32x4){0.f, 0.f, 0.f, 0.f};
#pragma unroll
        for (int c = 0; c < 2; ++c) {
            union { int i[4]; bf16x8 v; } bu;
#pragma unroll
            for (int d = 0; d < 4; ++d) {
                int src = (qb + (d >> 1)) * 16 + nl;
                int t0 = __shfl(pk[2 * c][d & 1], src);
                int t1 = __shfl(pk[2 * c + 1][d & 1], src);
                bu.i[d] = qh ? t1 : t0;
            }
#pragma unroll
            for (int T = 0; T < 4; ++T)
                a2[T] = __builtin_amdgcn_mfma_f32_16x16x32_bf16(w2f[c][T], bu.v, a2[T], 0, 0, 0);
        }
#pragma unroll
        for (int T = 0; T < 4; ++T) {
            const float4 bq = *(const float4*)&sb2[T * 16 + fq];
            dhT[(T * 16 + fq + 0) * 65 + w * 16 + nl] = a2[T][0] + bq.x;
            dhT[(T * 16 + fq + 1) * 65 + w * 16 + nl] = a2[T][1] + bq.y;
            dhT[(T * 16 + fq + 2) * 65 + w * 16 + nl] = a2[T][2] + bq.z;
            dhT[(T * 16 + fq + 3) * 65 + w * 16 + nl] = a2[T][3] + bq.w;
        }
        __syncthreads();
        {
            int n = base + ge;
            if (n < Nn) {
#pragma unroll
                for (int j = 0; j < 4; ++j) {
                    int f = part * 16 + j * 4;
                    float4* hp = (float4*)(h + ((size_t)n << 6) + f);
                    float4 old = *hp;
                    old.x += dhT[(f + 0) * 65 + ge];
                    old.y += dhT[(f + 1) * 65 + ge];
                    old.z += dhT[(f + 2) * 65 + ge];
                    old.w += dhT[(f + 3) * 65 + ge];
                    *hp = old;
                    bf16x4 hv = {(bf16)old.x, (bf16)old.y, (bf16)old.z, (bf16)old.w};
                    *(bf16x4*)(hbuf + ((size_t)n << 6) + f) = hv;
                }
            }
        }
        if (t < 64) {
            int n = base + t;
            if (n < Nn) {
#pragma unroll
                for (int c = 0; c < 3; ++c) x[n * 3 + c] += x_acc[n * 3 + c];
            }
        }
    }
}

// ---------------- readout q (MFMA) ----------------
__global__ __launch_bounds__(256) void k_q(
    const bf16* __restrict__ hbuf, const bf16* __restrict__ pq1,
    const float* __restrict__ b1v, const float* __restrict__ w2v,
    const float* __restrict__ b2v, float* __restrict__ qout) {
    __shared__ __align__(16) bf16 inB[8 * 64 * 8];
    __shared__ __align__(16) float sb1[64], sw2[64];
    const int t = threadIdx.x;
    const int l = t & 63, w = t >> 6, q = l >> 4, nl = l & 15;
    const int fq = 4 * q;
    const int ge = t >> 2, part = t & 3;

    bf16x8 w1f[2][4];
#pragma unroll
    for (int kc = 0; kc < 2; ++kc)
#pragma unroll
        for (int T = 0; T < 4; ++T)
            w1f[kc][T] = *(const bf16x8*)(pq1 + (((kc * 4 + T) * 64 + l) << 3));
    if (t < 64) { sb1[t] = b1v[t]; sw2[t] = w2v[t]; }
    const float qb2 = b2v[0];

    const int base = blockIdx.x * 64;
    {
        int n = base + ge;
        if (n < Nn) {
            const bf16* hr = hbuf + ((size_t)n << 6) + part * 16;
            *(bf16x8*)&inB[(((part * 2 + 0) * 64) + ge) << 3] = *(const bf16x8*)(hr);
            *(bf16x8*)&inB[(((part * 2 + 1) * 64) + ge) << 3] = *(const bf16x8*)(hr + 8);
        } else {
            bf16x8 zz = {(bf16)0.f, (bf16)0.f, (bf16)0.f, (bf16)0.f,
                         (bf16)0.f, (bf16)0.f, (bf16)0.f, (bf16)0.f};
            *(bf16x8*)&inB[(((part * 2 + 0) * 64) + ge) << 3] = zz;
            *(bf16x8*)&inB[(((part * 2 + 1) * 64) + ge) << 3] = zz;
        }
    }
    __syncthreads();
    f32x4 a1[4];
#pragma unroll
    for (int T = 0; T < 4; ++T) a1[T] = (f32x4){0.f, 0.f, 0.f, 0.f};
#pragma unroll
    for (int kc = 0; kc < 2; ++kc) {
        bf16x8 bfrag = *(const bf16x8*)&inB[(((kc * 4 + q) * 64) + w * 16 + nl) << 3];
#pragma unroll
        for (int T = 0; T < 4; ++T)
            a1[T] = __builtin_amdgcn_mfma_f32_16x16x32_bf16(w1f[kc][T], bfrag, a1[T], 0, 0, 0);
    }
    float pc = 0.f;
#pragma unroll
    for (int T = 0; T < 4; ++T) {
        const float4 bq = *(const float4*)&sb1[T * 16 + fq];
        const float4 cq = *(const float4*)&sw2[T * 16 + fq];
        pc += silu_f(a1[T][0] + bq.x) * cq.x;
        pc += silu_f(a1[T][1] + bq.y) * cq.y;
        pc += silu_f(a1[T][2] + bq.z) * cq.z;
        pc += silu_f(a1[T][3] + bq.w) * cq.w;
    }
    pc += __shfl_xor(pc, 16);
    pc += __shfl_xor(pc, 32);
    if (q == 0) {
        int n = base + w * 16 + nl;
        if (n < Nn) qout[n] = pc + qb2;
    }
}

// ---------------- batch stats & dipole ----------------
__global__ void k_batch(const int* __restrict__ batch, const float* __restrict__ x,
                        float* __restrict__ cnt, float* __restrict__ xs) {
    int n = blockIdx.x * blockDim.x + threadIdx.x;
    if (n < Nn) {
        int b = batch[n];
        atomicAdd(&cnt[b], 1.f);
        atomicAdd(&xs[b * 3 + 0], x[n * 3 + 0]);
        atomicAdd(&xs[b * 3 + 1], x[n * 3 + 1]);
        atomicAdd(&xs[b * 3 + 2], x[n * 3 + 2]);
    }
}

__global__ void k_mu(const int* __restrict__ batch, const float* __restrict__ x,
                     const float* __restrict__ q, const float* __restrict__ cnt,
                     const float* __restrict__ xs, float* __restrict__ out) {
    int n = blockIdx.x * blockDim.x + threadIdx.x;
    if (n < Nn) {
        int b = batch[n];
        float cc = fmaxf(cnt[b], 1.f);
        float qn = q[n];
#pragma unroll
        for (int c = 0; c < 3; ++c) {
            float xr = x[n * 3 + c] - xs[b * 3 + c] / cc;
            atomicAdd(&out[b * 3 + c], qn * xr);
        }
    }
}

// ---------------- launch ----------------
extern "C" void kernel_launch(void* const* d_in, const int* in_sizes, int n_in,
                              void* d_out, int out_size, void* d_ws, size_t ws_size,
                              hipStream_t stream) {
    const int* z = (const int*)d_in[0];
    const float* pos = (const float*)d_in[1];
    const int* ei0 = (const int*)d_in[2];
    const int* ei1 = ei0 + Ee;
    const int* batch = (const int*)d_in[3];
    const float* emb = (const float*)d_in[4];
    const float* eW1 = (const float*)d_in[5];
    const float* eb1 = (const float*)d_in[6];
    const float* eW2 = (const float*)d_in[7];
    const float* eb2 = (const float*)d_in[8];
    const float* cW = (const float*)d_in[9];
    const float* cb = (const float*)d_in[10];
    const float* nW1 = (const float*)d_in[11];
    const float* nb1 = (const float*)d_in[12];
    const float* nW2 = (const float*)d_in[13];
    const float* nb2 = (const float*)d_in[14];
    const float* qW1 = (const float*)d_in[15];
    const float* qb1 = (const float*)d_in[16];
    const float* qW2 = (const float*)d_in[17];
    const float* qb2 = (const float*)d_in[18];

    char* ws = (char*)d_ws;
    size_t o = 0;
    auto alloc = [&](size_t bytes) {
        size_t r = o;
        o = (o + bytes + 255) & ~(size_t)255;
        return r;
    };
    float* h = (float*)(ws + alloc((size_t)Nn * 64 * 4));
    float* xp = (float*)(ws + alloc((size_t)Nn * 3 * 4));
    float* magg = (float*)(ws + alloc((size_t)Nn * 64 * 4));
    float* xacc = (float*)(ws + alloc((size_t)Nn * 3 * 4));
    size_t zero_span = (size_t)((char*)xacc - (char*)magg) + (size_t)Nn * 3 * 4;
    float* qv = (float*)(ws + alloc((size_t)Nn * 4));
    int* deg = (int*)(ws + alloc((size_t)Nn * 4));
    int* rp = (int*)(ws + alloc((size_t)(Nn + 1) * 4));
    int* cur = (int*)(ws + alloc((size_t)Nn * 4));
    int* rows_s = (int*)(ws + alloc((size_t)Ee * 4));
    int* cols_s = (int*)(ws + alloc((size_t)Ee * 4));
    float* cnt = (float*)(ws + alloc((size_t)Bb * 4));
    float* xs = (float*)(ws + alloc((size_t)Bb * 3 * 4));
    bf16* hbm = (bf16*)(ws + alloc((size_t)Nn * 64 * 2));
    bf16* Pa = (bf16*)(ws + alloc((size_t)Nn * 64 * 2));
    bf16* Pb = (bf16*)(ws + alloc((size_t)Nn * 64 * 2));
    bf16* pw1 = (bf16*)(ws + alloc((size_t)4 * 8192 * 2));
    bf16* pw2 = (bf16*)(ws + alloc((size_t)4 * 4096 * 2));
    bf16* pn1 = (bf16*)(ws + alloc((size_t)4 * 8192 * 2));
    bf16* pn2 = (bf16*)(ws + alloc((size_t)4 * 4096 * 2));
    bf16* pq1 = (bf16*)(ws + alloc((size_t)4096 * 2));
    int* bsum = (int*)(ws + alloc((size_t)NB * 4));
    int* boff = (int*)(ws + alloc((size_t)NB * 4));

    hipMemsetAsync(deg, 0, (size_t)Nn * 4, stream);
    hipMemsetAsync(cnt, 0, (size_t)Bb * 4, stream);
    hipMemsetAsync(xs, 0, (size_t)Bb * 3 * 4, stream);
    hipMemsetAsync(d_out, 0, (size_t)out_size * 4, stream);

    k_init_h<<<(Nn * 64 + 255) / 256, 256, 0, stream>>>(h, hbm, z, emb);
    hipMemcpyAsync(xp, pos, (size_t)Nn * 3 * 4, hipMemcpyDeviceToDevice, stream);
    k_pack<<<(102400 + 255) / 256, 256, 0, stream>>>(eW1, eW2, nW1, nW2, qW1,
                                                     pw1, pw2, pn1, pn2, pq1);
    k_hist<<<(Ee + 255) / 256, 256, 0, stream>>>(ei0, deg);
    k_scan1<<<NB, 256, 0, stream>>>(deg, bsum);
    k_scan2<<<1, 256, 0, stream>>>(bsum, boff);
    k_scan3<<<NB, 256, 0, stream>>>(deg, boff, rp);
    hipMemcpyAsync(cur, rp, (size_t)Nn * 4, hipMemcpyDeviceToDevice, stream);
    k_scatter<<<(Ee + 255) / 256, 256, 0, stream>>>(ei0, ei1, cur, cols_s);
    k_fillrows<<<(Nn + 255) / 256, 256, 0, stream>>>(rp, rows_s);

    for (int l = 0; l < 4; ++l) {
        hipMemsetAsync(magg, 0, zero_span, stream);
        k_proj<<<256, 256, 0, stream>>>(hbm, pw1 + (size_t)l * 8192, eb1 + l * 64, Pa, Pb);
        k_edge<<<2048, 256, 0, stream>>>(rows_s, cols_s, Pa, Pb, xp,
                                         pw2 + (size_t)l * 4096,
                                         eW1 + (size_t)l * 129 * 64,
                                         eb2 + l * 64,
                                         cW + l * 64, cb + l, magg, xacc);
        k_node<<<256, 256, 0, stream>>>(magg, xacc,
                                        pn1 + (size_t)l * 8192, pn2 + (size_t)l * 4096,
                                        nb1 + l * 64, nb2 + l * 64,
                                        h, hbm, xp);
    }
    k_q<<<(Nn + 63) / 64, 256, 0, stream>>>(hbm, pq1, qb1, qW2, qb2, qv);
    k_batch<<<(Nn + 255) / 256, 256, 0, stream>>>(batch, xp, cnt, xs);
    k_mu<<<(Nn + 255) / 256, 256, 0, stream>>>(batch, xp, qv, cnt, xs, (float*)d_out);
}

// Round 17
// 1044.370 us; speedup vs baseline: 1.0105x; 1.0105x over previous
//
#include <hip/hip_runtime.h>
#include <math.h>

#define Nn 50000
#define Ee 1600000
#define Bb 512
#define TE 64
#define NTILES (Ee / TE)
#define NB ((Nn + 255) / 256)

typedef __bf16 bf16;
typedef __bf16 bf16x8 __attribute__((ext_vector_type(8)));
typedef __bf16 bf16x4 __attribute__((ext_vector_type(4)));
typedef float f32x4 __attribute__((ext_vector_type(4)));

__device__ __forceinline__ float silu_f(float v) {
    return v * __builtin_amdgcn_rcpf(1.f + __expf(-v));
}
__device__ __forceinline__ float tanh_f(float x) {
    float e = __expf(2.f * x);
    return 1.f - 2.f * __builtin_amdgcn_rcpf(e + 1.f);
}
__device__ __forceinline__ int pack2bf(float a, float b) {
    unsigned short ua = __builtin_bit_cast(unsigned short, (bf16)a);
    unsigned short ub = __builtin_bit_cast(unsigned short, (bf16)b);
    return (int)ua | ((int)ub << 16);
}
__device__ __forceinline__ float unlo(int v) {
    return __builtin_bit_cast(float, v << 16);
}
__device__ __forceinline__ float unhi(int v) {
    return __builtin_bit_cast(float, v & 0xffff0000);
}

// ---------------- init: h = emb[z] (fp32 + bf16 mirror) ----------------
__global__ void k_init_h(float* __restrict__ h, bf16* __restrict__ hb,
                         const int* __restrict__ z, const float* __restrict__ emb) {
    int i = blockIdx.x * blockDim.x + threadIdx.x;
    if (i < Nn * 64) {
        int n = i >> 6, f = i & 63;
        float v = emb[z[n] * 64 + f];
        h[i] = v;
        hb[i] = (bf16)v;
    }
}

// ---------------- weight packing into MFMA A-fragment order ----------------
__device__ __forceinline__ void packfrag(bf16* dst, const float* src, int idx) {
    int j = idx & 7, lane = (idx >> 3) & 63, gT = idx >> 9;
    int kc = gT >> 2, T = gT & 3;
    int k = kc * 32 + (lane >> 4) * 8 + j;
    int n = T * 16 + (lane & 15);
    dst[idx] = (bf16)src[k * 64 + n];
}

__global__ void k_pack(const float* __restrict__ eW1, const float* __restrict__ eW2,
                       const float* __restrict__ nW1, const float* __restrict__ nW2,
                       const float* __restrict__ qW1,
                       bf16* __restrict__ pw1, bf16* __restrict__ pw2,
                       bf16* __restrict__ pn1, bf16* __restrict__ pn2,
                       bf16* __restrict__ pq1) {
    int tid = blockIdx.x * blockDim.x + threadIdx.x;
    if (tid < 32768) {
        int l = tid >> 13, idx = tid & 8191;
        packfrag(pw1 + l * 8192, eW1 + (size_t)l * 129 * 64, idx);
    } else if (tid < 49152) {
        int i = tid - 32768, l = i >> 12, idx = i & 4095;
        packfrag(pw2 + l * 4096, eW2 + (size_t)l * 4096, idx);
    } else if (tid < 81920) {
        int i = tid - 49152, l = i >> 13, idx = i & 8191;
        packfrag(pn1 + l * 8192, nW1 + (size_t)l * 8192, idx);
    } else if (tid < 98304) {
        int i = tid - 81920, l = i >> 12, idx = i & 4095;
        packfrag(pn2 + l * 4096, nW2 + (size_t)l * 4096, idx);
    } else if (tid < 102400) {
        packfrag(pq1, qW1, tid - 98304);
    }
}

// ---------------- CSR build ----------------
__global__ void k_hist(const int* __restrict__ rows, int* __restrict__ deg) {
    int e = blockIdx.x * blockDim.x + threadIdx.x;
    if (e < Ee) atomicAdd(&deg[rows[e]], 1);
}

__global__ void k_scan1(const int* __restrict__ deg, int* __restrict__ bsum) {
    __shared__ int red[4];
    int b = blockIdx.x;
    int i = b * 256 + threadIdx.x;
    int v = (i < Nn) ? deg[i] : 0;
#pragma unroll
    for (int off = 1; off < 64; off <<= 1) v += __shfl_xor(v, off);
    if ((threadIdx.x & 63) == 0) red[threadIdx.x >> 6] = v;
    __syncthreads();
    if (threadIdx.x == 0) bsum[b] = red[0] + red[1] + red[2] + red[3];
}

__global__ void k_scan2(const int* __restrict__ bsum, int* __restrict__ boff) {
    __shared__ int s[256];
    int t = threadIdx.x;
    int v = (t < NB) ? bsum[t] : 0;
    s[t] = v;
    __syncthreads();
    for (int off = 1; off < 256; off <<= 1) {
        int u = (t >= off) ? s[t - off] : 0;
        __syncthreads();
        s[t] += u;
        __syncthreads();
    }
    if (t < NB) boff[t] = s[t] - v;
}

__global__ void k_scan3(const int* __restrict__ deg, const int* __restrict__ boff,
                        int* __restrict__ rp) {
    __shared__ int s[256];
    int b = blockIdx.x, t = threadIdx.x;
    int i = b * 256 + t;
    int v = (i < Nn) ? deg[i] : 0;
    s[t] = v;
    __syncthreads();
    for (int off = 1; off < 256; off <<= 1) {
        int u = (t >= off) ? s[t - off] : 0;
        __syncthreads();
        s[t] += u;
        __syncthreads();
    }
    if (i < Nn) rp[i] = boff[b] + s[t] - v;
    if (i == Nn - 1) rp[Nn] = boff[b] + s[t];
}

// cols-only scatter; cur preloaded with rp so atomic returns absolute offset
__global__ void k_scatter(const int* __restrict__ rows, const int* __restrict__ cols,
                          int* __restrict__ cur, int* __restrict__ cols_s) {
    int e = blockIdx.x * blockDim.x + threadIdx.x;
    if (e < Ee) {
        int o = atomicAdd(&cur[rows[e]], 1);
        cols_s[o] = cols[e];
    }
}

// rows_s expansion from rp (deterministic, sequential writes)
__global__ void k_fillrows(const int* __restrict__ rp, int* __restrict__ rows_s) {
    int n = blockIdx.x * blockDim.x + threadIdx.x;
    if (n < Nn) {
        int st = rp[n], en = rp[n + 1];
        for (int o = st; o < en; ++o) rows_s[o] = n;
    }
}

// ---------------- layer-0 node projection: Pa = H@W1a + b1, Pb = H@W1b (bf16 out) ----------------
__global__ __launch_bounds__(256) void k_proj(
    const bf16* __restrict__ hbuf, const bf16* __restrict__ pw1l,
    const float* __restrict__ b1v,
    bf16* __restrict__ Pa, bf16* __restrict__ Pb) {
    __shared__ __align__(16) bf16 inB[8 * 64 * 8];   // h B-frags
    __shared__ float dhT[64 * 65];
    __shared__ __align__(16) float sb1[64];

    const int t = threadIdx.x;
    const int l = t & 63, w = t >> 6, q = l >> 4, nl = l & 15;
    const int fq = 4 * q;
    const int ge = t >> 2, part = t & 3;

    bf16x8 w1f[4][4];
#pragma unroll
    for (int kc = 0; kc < 4; ++kc)
#pragma unroll
        for (int T = 0; T < 4; ++T)
            w1f[kc][T] = *(const bf16x8*)(pw1l + (((kc * 4 + T) * 64 + l) << 3));
    if (t < 64) sb1[t] = b1v[t];

    const int NT = (Nn + 63) / 64;
    for (int bt = blockIdx.x; bt < NT; bt += gridDim.x) {
        const int base = bt * 64;
        __syncthreads();  // protect inB/dhT reuse
        {
            int n = base + ge;
            if (n < Nn) {
                const bf16* hr = hbuf + ((size_t)n << 6) + part * 16;
                *(bf16x8*)&inB[(((part * 2 + 0) * 64) + ge) << 3] = *(const bf16x8*)(hr);
                *(bf16x8*)&inB[(((part * 2 + 1) * 64) + ge) << 3] = *(const bf16x8*)(hr + 8);
            } else {
                bf16x8 zz = {(bf16)0.f, (bf16)0.f, (bf16)0.f, (bf16)0.f,
                             (bf16)0.f, (bf16)0.f, (bf16)0.f, (bf16)0.f};
                *(bf16x8*)&inB[(((part * 2 + 0) * 64) + ge) << 3] = zz;
                *(bf16x8*)&inB[(((part * 2 + 1) * 64) + ge) << 3] = zz;
            }
        }
        __syncthreads();

        f32x4 apa[4], apb[4];
#pragma unroll
        for (int T = 0; T < 4; ++T) {
            apa[T] = (f32x4){0.f, 0.f, 0.f, 0.f};
            apb[T] = (f32x4){0.f, 0.f, 0.f, 0.f};
        }
#pragma unroll
        for (int kc = 0; kc < 2; ++kc) {
            bf16x8 bfrag = *(const bf16x8*)&inB[(((kc * 4 + q) * 64) + w * 16 + nl) << 3];
#pragma unroll
            for (int T = 0; T < 4; ++T) {
                apa[T] = __builtin_amdgcn_mfma_f32_16x16x32_bf16(w1f[kc][T], bfrag, apa[T], 0, 0, 0);
                apb[T] = __builtin_amdgcn_mfma_f32_16x16x32_bf16(w1f[kc + 2][T], bfrag, apb[T], 0, 0, 0);
            }
        }
#pragma unroll
        for (int T = 0; T < 4; ++T) {
#pragma unroll
            for (int r = 0; r < 4; ++r)
                dhT[(T * 16 + fq + r) * 65 + w * 16 + nl] = apa[T][r] + sb1[T * 16 + fq + r];
        }
        __syncthreads();
        {
            int n = base + ge;
            if (n < Nn) {
#pragma unroll
                for (int j = 0; j < 4; ++j) {
                    int f = part * 16 + j * 4;
                    bf16x4 bv = {(bf16)dhT[(f + 0) * 65 + ge], (bf16)dhT[(f + 1) * 65 + ge],
                                 (bf16)dhT[(f + 2) * 65 + ge], (bf16)dhT[(f + 3) * 65 + ge]};
                    *(bf16x4*)(Pa + ((size_t)n << 6) + f) = bv;
                }
            }
        }
        __syncthreads();
#pragma unroll
        for (int T = 0; T < 4; ++T) {
#pragma unroll
            for (int r = 0; r < 4; ++r)
                dhT[(T * 16 + fq + r) * 65 + w * 16 + nl] = apb[T][r];
        }
        __syncthreads();
        {
            int n = base + ge;
            if (n < Nn) {
#pragma unroll
                for (int j = 0; j < 4; ++j) {
                    int f = part * 16 + j * 4;
                    bf16x4 bv = {(bf16)dhT[(f + 0) * 65 + ge], (bf16)dhT[(f + 1) * 65 + ge],
                                 (bf16)dhT[(f + 2) * 65 + ge], (bf16)dhT[(f + 3) * 65 + ge]};
                    *(bf16x4*)(Pb + ((size_t)n << 6) + f) = bv;
                }
            }
        }
    }
}

// ---------------- edge kernel: gather bf16 Pa/Pb + rank-1 + silu -> GEMM2 only ----------------
__global__ __launch_bounds__(256, 8) void k_edge(
    const int* __restrict__ rows_s, const int* __restrict__ cols_s,
    const bf16* __restrict__ Pa, const bf16* __restrict__ Pb,
    const float* __restrict__ x,
    const bf16* __restrict__ pw2l,
    const float* __restrict__ w1f32,
    const float* __restrict__ b2v,
    const float* __restrict__ cwv, const float* __restrict__ cbv,
    float* __restrict__ m_agg, float* __restrict__ x_acc) {
    __shared__ __align__(16) bf16 lw2[4096];   // 8 KB GEMM2 A-frags
    __shared__ __align__(16) float w128s[64], b2s[64], cws[64];
    __shared__ int mEp[32 * 65];               // packed bf16x2 [featpair][edge]
    __shared__ __align__(16) float relsm[64 * 4];
    __shared__ float coefs[64];
    __shared__ int srow[64];

    const int t = threadIdx.x;
    const int l = t & 63, w = t >> 6, q = l >> 4, nl = l & 15;
    const int fq = 4 * q;
    const int ge = l >> 2, part = l & 3;   // gather roles within wave

    // stage GEMM2 weights + tables into LDS (once)
    {
        const int4* s2 = (const int4*)pw2l;
        int4* d2p = (int4*)lw2;
#pragma unroll
        for (int i = 0; i < 2; ++i) d2p[t + 256 * i] = s2[t + 256 * i];
        if (t < 64) {
            w128s[t] = w1f32[128 * 64 + t];
            b2s[t] = b2v[t];
            cws[t] = cwv[t];
        }
    }
    const float cb0 = cbv[0];
    __syncthreads();

    for (int tile = blockIdx.x; tile < NTILES; tile += gridDim.x) {
        const int eo = tile * TE + w * 16;

        const int r_g = rows_s[eo + ge], c_g = cols_s[eo + ge];
        float rx = x[r_g * 3 + 0] - x[c_g * 3 + 0];
        float ry = x[r_g * 3 + 1] - x[c_g * 3 + 1];
        float rz = x[r_g * 3 + 2] - x[c_g * 3 + 2];
        float d2 = fmaf(rx, rx, fmaf(ry, ry, rz * rz));
        if (part == 0) {
            srow[w * 16 + ge] = r_g;
            float4 rv;
            rv.x = rx; rv.y = ry; rv.z = rz; rv.w = d2;
            *(float4*)&relsm[(w * 16 + ge) * 4] = rv;
        }

        const bf16* par = Pa + ((size_t)r_g << 6) + part * 16;
        const bf16* pbc = Pb + ((size_t)c_g << 6) + part * 16;
        int4 Ai = *(const int4*)(par);
        int4 Aj = *(const int4*)(par + 8);
        int4 Bi = *(const int4*)(pbc);
        int4 Bj = *(const int4*)(pbc + 8);
        const float4 w0 = *(const float4*)&w128s[part * 16 + 0];
        const float4 w1 = *(const float4*)&w128s[part * 16 + 4];
        const float4 w2q = *(const float4*)&w128s[part * 16 + 8];
        const float4 w3 = *(const float4*)&w128s[part * 16 + 12];

        int pk[8];
        pk[0] = pack2bf(silu_f(fmaf(w0.x, d2, unlo(Ai.x) + unlo(Bi.x))),
                        silu_f(fmaf(w0.y, d2, unhi(Ai.x) + unhi(Bi.x))));
        pk[1] = pack2bf(silu_f(fmaf(w0.z, d2, unlo(Ai.y) + unlo(Bi.y))),
                        silu_f(fmaf(w0.w, d2, unhi(Ai.y) + unhi(Bi.y))));
        pk[2] = pack2bf(silu_f(fmaf(w1.x, d2, unlo(Ai.z) + unlo(Bi.z))),
                        silu_f(fmaf(w1.y, d2, unhi(Ai.z) + unhi(Bi.z))));
        pk[3] = pack2bf(silu_f(fmaf(w1.z, d2, unlo(Ai.w) + unlo(Bi.w))),
                        silu_f(fmaf(w1.w, d2, unhi(Ai.w) + unhi(Bi.w))));
        pk[4] = pack2bf(silu_f(fmaf(w2q.x, d2, unlo(Aj.x) + unlo(Bj.x))),
                        silu_f(fmaf(w2q.y, d2, unhi(Aj.x) + unhi(Bj.x))));
        pk[5] = pack2bf(silu_f(fmaf(w2q.z, d2, unlo(Aj.y) + unlo(Bj.y))),
                        silu_f(fmaf(w2q.w, d2, unhi(Aj.y) + unhi(Bj.y))));
        pk[6] = pack2bf(silu_f(fmaf(w3.x, d2, unlo(Aj.z) + unlo(Bj.z))),
                        silu_f(fmaf(w3.y, d2, unhi(Aj.z) + unhi(Bj.z))));
        pk[7] = pack2bf(silu_f(fmaf(w3.z, d2, unlo(Aj.w) + unlo(Bj.w))),
                        silu_f(fmaf(w3.w, d2, unhi(Aj.w) + unhi(Bj.w))));

        f32x4 a2[4];
#pragma unroll
        for (int T = 0; T < 4; ++T) a2[T] = (f32x4){0.f, 0.f, 0.f, 0.f};
#pragma unroll
        for (int c2 = 0; c2 < 2; ++c2) {
            union { int i[4]; bf16x8 v; } bu;
            int src = nl * 4 + 2 * c2 + (q >> 1);
#pragma unroll
            for (int d = 0; d < 4; ++d) {
                int t0 = __shfl(pk[d], src);
                int t1 = __shfl(pk[4 + d], src);
                bu.i[d] = (q & 1) ? t1 : t0;
            }
#pragma unroll
            for (int T = 0; T < 4; ++T) {
                bf16x8 wf = *(const bf16x8*)&lw2[(((c2 * 4 + T) * 64) + l) << 3];
                a2[T] = __builtin_amdgcn_mfma_f32_16x16x32_bf16(wf, bu.v, a2[T], 0, 0, 0);
            }
        }
        float pc = 0.f;
#pragma unroll
        for (int T = 0; T < 4; ++T) {
            const float4 bq = *(const float4*)&b2s[T * 16 + fq];
            const float4 cq = *(const float4*)&cws[T * 16 + fq];
            float m0 = silu_f(a2[T][0] + bq.x);
            float m1 = silu_f(a2[T][1] + bq.y);
            float m2 = silu_f(a2[T][2] + bq.z);
            float m3 = silu_f(a2[T][3] + bq.w);
            int p0 = (T * 16 + fq) >> 1;
            mEp[(p0 + 0) * 65 + w * 16 + nl] = pack2bf(m0, m1);
            mEp[(p0 + 1) * 65 + w * 16 + nl] = pack2bf(m2, m3);
            pc += m0 * cq.x + m1 * cq.y + m2 * cq.z + m3 * cq.w;
        }
        pc += __shfl_xor(pc, 16);
        pc += __shfl_xor(pc, 32);
        if (q == 0) coefs[w * 16 + nl] = tanh_f(pc + cb0);
        __syncthreads();  // barrier A

        {
            int rl = srow[l];
            int rprev = __shfl(rl, l - 1);
            bool isst = (l == 0) || (rl != rprev);
            unsigned long long mask = __ballot(isst);
            const int pair = l & 31, half = l >> 5;
            unsigned long long mm = mask;
            int s = 0;
            while (mm) {
                int st = __ffsll(mm) - 1;
                mm &= mm - 1;
                if ((s & 3) == w) {
                    int en = mm ? (__ffsll(mm) - 1) : TE;
                    int row = __shfl(rl, st);
                    float s0 = 0.f, s1 = 0.f, sx = 0.f;
                    for (int e = st + half; e < en; e += 2) {
                        int pv = mEp[pair * 65 + e];
                        s0 += __builtin_bit_cast(float, pv << 16);
                        s1 += __builtin_bit_cast(float, pv & 0xffff0000);
                    }
                    if (half == 1 && pair < 3) {
                        for (int e = st; e < en; ++e)
                            sx += relsm[e * 4 + pair] * coefs[e];
                    }
                    s0 += __shfl_xor(s0, 32);
                    s1 += __shfl_xor(s1, 32);
                    if (half == 0) {
                        atomicAdd(m_agg + (size_t)row * 64 + 2 * pair, s0);
                        atomicAdd(m_agg + (size_t)row * 64 + 2 * pair + 1, s1);
                    } else if (pair < 3) {
                        atomicAdd(x_acc + (size_t)row * 3 + pair, sx);
                    }
                }
                s++;
            }
        }
        __syncthreads();  // barrier B
    }
}

// ---------------- node kernel (MFMA, grid-stride; fused next-layer projection) ----------------
__global__ __launch_bounds__(256) void k_node(
    const float* __restrict__ m_agg, const float* __restrict__ x_acc,
    const bf16* __restrict__ pn1l, const bf16* __restrict__ pn2l,
    const float* __restrict__ b1v, const float* __restrict__ b2v,
    float* __restrict__ h, bf16* __restrict__ hbuf, float* __restrict__ x,
    const bf16* __restrict__ pw1n, const float* __restrict__ b1n,
    bf16* __restrict__ Pa, bf16* __restrict__ Pb, int donext) {
    __shared__ __align__(16) bf16 inB[16 * 64 * 8];
    __shared__ float dhT[64 * 65];
    __shared__ __align__(16) float sb1[64], sb2[64], sb1n[64];

    const int t = threadIdx.x;
    const int l = t & 63, w = t >> 6, q = l >> 4, nl = l & 15;
    const int qh = q >> 1, qb = 2 * (q & 1), fq = 4 * q;
    const int ge = t >> 2, part = t & 3;

    bf16x8 w1f[4][4];
#pragma unroll
    for (int kc = 0; kc < 4; ++kc)
#pragma unroll
        for (int T = 0; T < 4; ++T)
            w1f[kc][T] = *(const bf16x8*)(pn1l + (((kc * 4 + T) * 64 + l) << 3));
    bf16x8 w2f[2][4];
#pragma unroll
    for (int c = 0; c < 2; ++c)
#pragma unroll
        for (int T = 0; T < 4; ++T)
            w2f[c][T] = *(const bf16x8*)(pn2l + (((c * 4 + T) * 64 + l) << 3));
    if (t < 64) { sb1[t] = b1v[t]; sb2[t] = b2v[t]; sb1n[t] = b1n[t]; }

    const int NT = (Nn + 63) / 64;
    for (int bt = blockIdx.x; bt < NT; bt += gridDim.x) {
        const int base = bt * 64;
        const int n_g = base + ge;
        __syncthreads();  // protect inB reuse across iterations
        {
            if (n_g < Nn) {
                const bf16* hr = hbuf + ((size_t)n_g << 6) + part * 16;
                *(bf16x8*)&inB[(((part * 2 + 0) * 64) + ge) << 3] = *(const bf16x8*)(hr);
                *(bf16x8*)&inB[(((part * 2 + 1) * 64) + ge) << 3] = *(const bf16x8*)(hr + 8);
                const float* mr = m_agg + ((size_t)n_g << 6) + part * 16;
                float4 m0 = *(const float4*)(mr + 0);
                float4 m1 = *(const float4*)(mr + 4);
                float4 m2 = *(const float4*)(mr + 8);
                float4 m3 = *(const float4*)(mr + 12);
                bf16x8 bm0 = {(bf16)m0.x, (bf16)m0.y, (bf16)m0.z, (bf16)m0.w,
                              (bf16)m1.x, (bf16)m1.y, (bf16)m1.z, (bf16)m1.w};
                bf16x8 bm1 = {(bf16)m2.x, (bf16)m2.y, (bf16)m2.z, (bf16)m2.w,
                              (bf16)m3.x, (bf16)m3.y, (bf16)m3.z, (bf16)m3.w};
                *(bf16x8*)&inB[(((8 + part * 2 + 0) * 64) + ge) << 3] = bm0;
                *(bf16x8*)&inB[(((8 + part * 2 + 1) * 64) + ge) << 3] = bm1;
            } else {
                bf16x8 zz = {(bf16)0.f, (bf16)0.f, (bf16)0.f, (bf16)0.f,
                             (bf16)0.f, (bf16)0.f, (bf16)0.f, (bf16)0.f};
                *(bf16x8*)&inB[(((part * 2 + 0) * 64) + ge) << 3] = zz;
                *(bf16x8*)&inB[(((part * 2 + 1) * 64) + ge) << 3] = zz;
                *(bf16x8*)&inB[(((8 + part * 2 + 0) * 64) + ge) << 3] = zz;
                *(bf16x8*)&inB[(((8 + part * 2 + 1) * 64) + ge) << 3] = zz;
            }
        }
        __syncthreads();

        f32x4 a1[4];
#pragma unroll
        for (int T = 0; T < 4; ++T) a1[T] = (f32x4){0.f, 0.f, 0.f, 0.f};
#pragma unroll
        for (int kc = 0; kc < 4; ++kc) {
            bf16x8 bfrag = *(const bf16x8*)&inB[(((kc * 4 + q) * 64) + w * 16 + nl) << 3];
#pragma unroll
            for (int T = 0; T < 4; ++T)
                a1[T] = __builtin_amdgcn_mfma_f32_16x16x32_bf16(w1f[kc][T], bfrag, a1[T], 0, 0, 0);
        }
        int pk[4][2];
#pragma unroll
        for (int T = 0; T < 4; ++T) {
            const float4 bq = *(const float4*)&sb1[T * 16 + fq];
            float h0 = silu_f(a1[T][0] + bq.x);
            float h1 = silu_f(a1[T][1] + bq.y);
            float h2 = silu_f(a1[T][2] + bq.z);
            float h3 = silu_f(a1[T][3] + bq.w);
            pk[T][0] = pack2bf(h0, h1);
            pk[T][1] = pack2bf(h2, h3);
        }
        f32x4 a2[4];
#pragma unroll
        for (int T = 0; T < 4; ++T) a2[T] = (f32x4){0.f, 0.f, 0.f, 0.f};
#pragma unroll
        for (int c = 0; c < 2; ++c) {
            union { int i[4]; bf16x8 v; } bu;
#pragma unroll
            for (int d = 0; d < 4; ++d) {
                int src = (qb + (d >> 1)) * 16 + nl;
                int t0 = __shfl(pk[2 * c][d & 1], src);
                int t1 = __shfl(pk[2 * c + 1][d & 1], src);
                bu.i[d] = qh ? t1 : t0;
            }
#pragma unroll
            for (int T = 0; T < 4; ++T)
                a2[T] = __builtin_amdgcn_mfma_f32_16x16x32_bf16(w2f[c][T], bu.v, a2[T], 0, 0, 0);
        }
#pragma unroll
        for (int T = 0; T < 4; ++T) {
            const float4 bq = *(const float4*)&sb2[T * 16 + fq];
            dhT[(T * 16 + fq + 0) * 65 + w * 16 + nl] = a2[T][0] + bq.x;
            dhT[(T * 16 + fq + 1) * 65 + w * 16 + nl] = a2[T][1] + bq.y;
            dhT[(T * 16 + fq + 2) * 65 + w * 16 + nl] = a2[T][2] + bq.z;
            dhT[(T * 16 + fq + 3) * 65 + w * 16 + nl] = a2[T][3] + bq.w;
        }
        __syncthreads();
        // h += dh; write fp32 + bf16; stage new-h bf16 into inB for fused projection
        {
            if (n_g < Nn) {
                bf16x4 hv[4];
#pragma unroll
                for (int j = 0; j < 4; ++j) {
                    int f = part * 16 + j * 4;
                    float4* hp = (float4*)(h + ((size_t)n_g << 6) + f);
                    float4 old = *hp;
                    old.x += dhT[(f + 0) * 65 + ge];
                    old.y += dhT[(f + 1) * 65 + ge];
                    old.z += dhT[(f + 2) * 65 + ge];
                    old.w += dhT[(f + 3) * 65 + ge];
                    *hp = old;
                    hv[j] = (bf16x4){(bf16)old.x, (bf16)old.y, (bf16)old.z, (bf16)old.w};
                    *(bf16x4*)(hbuf + ((size_t)n_g << 6) + f) = hv[j];
                }
                if (donext) {
                    union { bf16x4 h2[2]; bf16x8 v; } u0, u1;
                    u0.h2[0] = hv[0]; u0.h2[1] = hv[1];
                    u1.h2[0] = hv[2]; u1.h2[1] = hv[3];
                    *(bf16x8*)&inB[(((part * 2 + 0) * 64) + ge) << 3] = u0.v;
                    *(bf16x8*)&inB[(((part * 2 + 1) * 64) + ge) << 3] = u1.v;
                }
            } else if (donext) {
                bf16x8 zz = {(bf16)0.f, (bf16)0.f, (bf16)0.f, (bf16)0.f,
                             (bf16)0.f, (bf16)0.f, (bf16)0.f, (bf16)0.f};
                *(bf16x8*)&inB[(((part * 2 + 0) * 64) + ge) << 3] = zz;
                *(bf16x8*)&inB[(((part * 2 + 1) * 64) + ge) << 3] = zz;
            }
        }
        if (t < 64) {
            int n = base + t;
            if (n < Nn) {
#pragma unroll
                for (int c = 0; c < 3; ++c) x[n * 3 + c] += x_acc[n * 3 + c];
            }
        }
        if (!donext) continue;
        __syncthreads();
        // fused projection for next layer: Pa = Hnew@W1a + b1n, Pb = Hnew@W1b
        f32x4 apa[4], apb[4];
#pragma unroll
        for (int T = 0; T < 4; ++T) {
            apa[T] = (f32x4){0.f, 0.f, 0.f, 0.f};
            apb[T] = (f32x4){0.f, 0.f, 0.f, 0.f};
        }
#pragma unroll
        for (int kc = 0; kc < 2; ++kc) {
            bf16x8 bfrag = *(const bf16x8*)&inB[(((kc * 4 + q) * 64) + w * 16 + nl) << 3];
#pragma unroll
            for (int T = 0; T < 4; ++T) {
                bf16x8 wa = *(const bf16x8*)(pw1n + (((kc * 4 + T) * 64 + l) << 3));
                bf16x8 wb = *(const bf16x8*)(pw1n + ((((kc + 2) * 4 + T) * 64 + l) << 3));
                apa[T] = __builtin_amdgcn_mfma_f32_16x16x32_bf16(wa, bfrag, apa[T], 0, 0, 0);
                apb[T] = __builtin_amdgcn_mfma_f32_16x16x32_bf16(wb, bfrag, apb[T], 0, 0, 0);
            }
        }
#pragma unroll
        for (int T = 0; T < 4; ++T) {
#pragma unroll
            for (int r = 0; r < 4; ++r)
                dhT[(T * 16 + fq + r) * 65 + w * 16 + nl] = apa[T][r] + sb1n[T * 16 + fq + r];
        }
        __syncthreads();
        if (n_g < Nn) {
#pragma unroll
            for (int j = 0; j < 4; ++j) {
                int f = part * 16 + j * 4;
                bf16x4 bv = {(bf16)dhT[(f + 0) * 65 + ge], (bf16)dhT[(f + 1) * 65 + ge],
                             (bf16)dhT[(f + 2) * 65 + ge], (bf16)dhT[(f + 3) * 65 + ge]};
                *(bf16x4*)(Pa + ((size_t)n_g << 6) + f) = bv;
            }
        }
        __syncthreads();
#pragma unroll
        for (int T = 0; T < 4; ++T) {
#pragma unroll
            for (int r = 0; r < 4; ++r)
                dhT[(T * 16 + fq + r) * 65 + w * 16 + nl] = apb[T][r];
        }
        __syncthreads();
        if (n_g < Nn) {
#pragma unroll
            for (int j = 0; j < 4; ++j) {
                int f = part * 16 + j * 4;
                bf16x4 bv = {(bf16)dhT[(f + 0) * 65 + ge], (bf16)dhT[(f + 1) * 65 + ge],
                             (bf16)dhT[(f + 2) * 65 + ge], (bf16)dhT[(f + 3) * 65 + ge]};
                *(bf16x4*)(Pb + ((size_t)n_g << 6) + f) = bv;
            }
        }
    }
}

// ---------------- readout q (MFMA) ----------------
__global__ __launch_bounds__(256) void k_q(
    const bf16* __restrict__ hbuf, const bf16* __restrict__ pq1,
    const float* __restrict__ b1v, const float* __restrict__ w2v,
    const float* __restrict__ b2v, float* __restrict__ qout) {
    __shared__ __align__(16) bf16 inB[8 * 64 * 8];
    __shared__ __align__(16) float sb1[64], sw2[64];
    const int t = threadIdx.x;
    const int l = t & 63, w = t >> 6, q = l >> 4, nl = l & 15;
    const int fq = 4 * q;
    const int ge = t >> 2, part = t & 3;

    bf16x8 w1f[2][4];
#pragma unroll
    for (int kc = 0; kc < 2; ++kc)
#pragma unroll
        for (int T = 0; T < 4; ++T)
            w1f[kc][T] = *(const bf16x8*)(pq1 + (((kc * 4 + T) * 64 + l) << 3));
    if (t < 64) { sb1[t] = b1v[t]; sw2[t] = w2v[t]; }
    const float qb2 = b2v[0];

    const int base = blockIdx.x * 64;
    {
        int n = base + ge;
        if (n < Nn) {
            const bf16* hr = hbuf + ((size_t)n << 6) + part * 16;
            *(bf16x8*)&inB[(((part * 2 + 0) * 64) + ge) << 3] = *(const bf16x8*)(hr);
            *(bf16x8*)&inB[(((part * 2 + 1) * 64) + ge) << 3] = *(const bf16x8*)(hr + 8);
        } else {
            bf16x8 zz = {(bf16)0.f, (bf16)0.f, (bf16)0.f, (bf16)0.f,
                         (bf16)0.f, (bf16)0.f, (bf16)0.f, (bf16)0.f};
            *(bf16x8*)&inB[(((part * 2 + 0) * 64) + ge) << 3] = zz;
            *(bf16x8*)&inB[(((part * 2 + 1) * 64) + ge) << 3] = zz;
        }
    }
    __syncthreads();
    f32x4 a1[4];
#pragma unroll
    for (int T = 0; T < 4; ++T) a1[T] = (f32x4){0.f, 0.f, 0.f, 0.f};
#pragma unroll
    for (int kc = 0; kc < 2; ++kc) {
        bf16x8 bfrag = *(const bf16x8*)&inB[(((kc * 4 + q) * 64) + w * 16 + nl) << 3];
#pragma unroll
        for (int T = 0; T < 4; ++T)
            a1[T] = __builtin_amdgcn_mfma_f32_16x16x32_bf16(w1f[kc][T], bfrag, a1[T], 0, 0, 0);
    }
    float pc = 0.f;
#pragma unroll
    for (int T = 0; T < 4; ++T) {
        const float4 bq = *(const float4*)&sb1[T * 16 + fq];
        const float4 cq = *(const float4*)&sw2[T * 16 + fq];
        pc += silu_f(a1[T][0] + bq.x) * cq.x;
        pc += silu_f(a1[T][1] + bq.y) * cq.y;
        pc += silu_f(a1[T][2] + bq.z) * cq.z;
        pc += silu_f(a1[T][3] + bq.w) * cq.w;
    }
    pc += __shfl_xor(pc, 16);
    pc += __shfl_xor(pc, 32);
    if (q == 0) {
        int n = base + w * 16 + nl;
        if (n < Nn) qout[n] = pc + qb2;
    }
}

// ---------------- batch stats & dipole ----------------
__global__ void k_batch(const int* __restrict__ batch, const float* __restrict__ x,
                        float* __restrict__ cnt, float* __restrict__ xs) {
    int n = blockIdx.x * blockDim.x + threadIdx.x;
    if (n < Nn) {
        int b = batch[n];
        atomicAdd(&cnt[b], 1.f);
        atomicAdd(&xs[b * 3 + 0], x[n * 3 + 0]);
        atomicAdd(&xs[b * 3 + 1], x[n * 3 + 1]);
        atomicAdd(&xs[b * 3 + 2], x[n * 3 + 2]);
    }
}

__global__ void k_mu(const int* __restrict__ batch, const float* __restrict__ x,
                     const float* __restrict__ q, const float* __restrict__ cnt,
                     const float* __restrict__ xs, float* __restrict__ out) {
    int n = blockIdx.x * blockDim.x + threadIdx.x;
    if (n < Nn) {
        int b = batch[n];
        float cc = fmaxf(cnt[b], 1.f);
        float qn = q[n];
#pragma unroll
        for (int c = 0; c < 3; ++c) {
            float xr = x[n * 3 + c] - xs[b * 3 + c] / cc;
            atomicAdd(&out[b * 3 + c], qn * xr);
        }
    }
}

// ---------------- launch ----------------
extern "C" void kernel_launch(void* const* d_in, const int* in_sizes, int n_in,
                              void* d_out, int out_size, void* d_ws, size_t ws_size,
                              hipStream_t stream) {
    const int* z = (const int*)d_in[0];
    const float* pos = (const float*)d_in[1];
    const int* ei0 = (const int*)d_in[2];
    const int* ei1 = ei0 + Ee;
    const int* batch = (const int*)d_in[3];
    const float* emb = (const float*)d_in[4];
    const float* eW1 = (const float*)d_in[5];
    const float* eb1 = (const float*)d_in[6];
    const float* eW2 = (const float*)d_in[7];
    const float* eb2 = (const float*)d_in[8];
    const float* cW = (const float*)d_in[9];
    const float* cb = (const float*)d_in[10];
    const float* nW1 = (const float*)d_in[11];
    const float* nb1 = (const float*)d_in[12];
    const float* nW2 = (const float*)d_in[13];
    const float* nb2 = (const float*)d_in[14];
    const float* qW1 = (const float*)d_in[15];
    const float* qb1 = (const float*)d_in[16];
    const float* qW2 = (const float*)d_in[17];
    const float* qb2 = (const float*)d_in[18];

    char* ws = (char*)d_ws;
    size_t o = 0;
    auto alloc = [&](size_t bytes) {
        size_t r = o;
        o = (o + bytes + 255) & ~(size_t)255;
        return r;
    };
    float* h = (float*)(ws + alloc((size_t)Nn * 64 * 4));
    float* xp = (float*)(ws + alloc((size_t)Nn * 3 * 4));
    float* magg = (float*)(ws + alloc((size_t)Nn * 64 * 4));
    float* xacc = (float*)(ws + alloc((size_t)Nn * 3 * 4));
    size_t zero_span = (size_t)((char*)xacc - (char*)magg) + (size_t)Nn * 3 * 4;
    float* qv = (float*)(ws + alloc((size_t)Nn * 4));
    int* deg = (int*)(ws + alloc((size_t)Nn * 4));
    int* rp = (int*)(ws + alloc((size_t)(Nn + 1) * 4));
    int* cur = (int*)(ws + alloc((size_t)Nn * 4));
    int* rows_s = (int*)(ws + alloc((size_t)Ee * 4));
    int* cols_s = (int*)(ws + alloc((size_t)Ee * 4));
    float* cnt = (float*)(ws + alloc((size_t)Bb * 4));
    float* xs = (float*)(ws + alloc((size_t)Bb * 3 * 4));
    bf16* hbm = (bf16*)(ws + alloc((size_t)Nn * 64 * 2));
    bf16* Pa = (bf16*)(ws + alloc((size_t)Nn * 64 * 2));
    bf16* Pb = (bf16*)(ws + alloc((size_t)Nn * 64 * 2));
    bf16* pw1 = (bf16*)(ws + alloc((size_t)4 * 8192 * 2));
    bf16* pw2 = (bf16*)(ws + alloc((size_t)4 * 4096 * 2));
    bf16* pn1 = (bf16*)(ws + alloc((size_t)4 * 8192 * 2));
    bf16* pn2 = (bf16*)(ws + alloc((size_t)4 * 4096 * 2));
    bf16* pq1 = (bf16*)(ws + alloc((size_t)4096 * 2));
    int* bsum = (int*)(ws + alloc((size_t)NB * 4));
    int* boff = (int*)(ws + alloc((size_t)NB * 4));

    hipMemsetAsync(deg, 0, (size_t)Nn * 4, stream);
    hipMemsetAsync(cnt, 0, (size_t)Bb * 4, stream);
    hipMemsetAsync(xs, 0, (size_t)Bb * 3 * 4, stream);
    hipMemsetAsync(d_out, 0, (size_t)out_size * 4, stream);

    k_init_h<<<(Nn * 64 + 255) / 256, 256, 0, stream>>>(h, hbm, z, emb);
    hipMemcpyAsync(xp, pos, (size_t)Nn * 3 * 4, hipMemcpyDeviceToDevice, stream);
    k_pack<<<(102400 + 255) / 256, 256, 0, stream>>>(eW1, eW2, nW1, nW2, qW1,
                                                     pw1, pw2, pn1, pn2, pq1);
    k_hist<<<(Ee + 255) / 256, 256, 0, stream>>>(ei0, deg);
    k_scan1<<<NB, 256, 0, stream>>>(deg, bsum);
    k_scan2<<<1, 256, 0, stream>>>(bsum, boff);
    k_scan3<<<NB, 256, 0, stream>>>(deg, boff, rp);
    hipMemcpyAsync(cur, rp, (size_t)Nn * 4, hipMemcpyDeviceToDevice, stream);
    k_scatter<<<(Ee + 255) / 256, 256, 0, stream>>>(ei0, ei1, cur, cols_s);
    k_fillrows<<<(Nn + 255) / 256, 256, 0, stream>>>(rp, rows_s);

    k_proj<<<256, 256, 0, stream>>>(hbm, pw1, eb1, Pa, Pb);
    for (int l = 0; l < 4; ++l) {
        hipMemsetAsync(magg, 0, zero_span, stream);
        k_edge<<<2048, 256, 0, stream>>>(rows_s, cols_s, Pa, Pb, xp,
                                         pw2 + (size_t)l * 4096,
                                         eW1 + (size_t)l * 129 * 64,
                                         eb2 + l * 64,
                                         cW + l * 64, cb + l, magg, xacc);
        int nx = (l < 3) ? (l + 1) : 0;
        k_node<<<256, 256, 0, stream>>>(magg, xacc,
                                        pn1 + (size_t)l * 8192, pn2 + (size_t)l * 4096,
                                        nb1 + l * 64, nb2 + l * 64,
                                        h, hbm, xp,
                                        pw1 + (size_t)nx * 8192, eb1 + nx * 64,
                                        Pa, Pb, (l < 3) ? 1 : 0);
    }
    k_q<<<(Nn + 63) / 64, 256, 0, stream>>>(hbm, pq1, qb1, qW2, qb2, qv);
    k_batch<<<(Nn + 255) / 256, 256, 0, stream>>>(batch, xp, cnt, xs);
    k_mu<<<(Nn + 255) / 256, 256, 0, stream>>>(batch, xp, qv, cnt, xs, (float*)d_out);
}

// Round 18
// 1031.317 us; speedup vs baseline: 1.0232x; 1.0127x over previous
//
#include <hip/hip_runtime.h>
#include <math.h>

#define Nn 50000
#define Ee 1600000
#define Bb 512
#define TE 64
#define NTILES (Ee / TE)
#define NB ((Nn + 255) / 256)

typedef __bf16 bf16;
typedef __bf16 bf16x8 __attribute__((ext_vector_type(8)));
typedef __bf16 bf16x4 __attribute__((ext_vector_type(4)));
typedef float f32x4 __attribute__((ext_vector_type(4)));

__device__ __forceinline__ float silu_f(float v) {
    return v * __builtin_amdgcn_rcpf(1.f + __expf(-v));
}
__device__ __forceinline__ float tanh_f(float x) {
    float e = __expf(2.f * x);
    return 1.f - 2.f * __builtin_amdgcn_rcpf(e + 1.f);
}
__device__ __forceinline__ int pack2bf(float a, float b) {
    unsigned short ua = __builtin_bit_cast(unsigned short, (bf16)a);
    unsigned short ub = __builtin_bit_cast(unsigned short, (bf16)b);
    return (int)ua | ((int)ub << 16);
}
__device__ __forceinline__ float unlo(int v) {
    return __builtin_bit_cast(float, v << 16);
}
__device__ __forceinline__ float unhi(int v) {
    return __builtin_bit_cast(float, v & 0xffff0000);
}

// ---------------- init: h = emb[z] (fp32 + bf16 mirror) ----------------
__global__ void k_init_h(float* __restrict__ h, bf16* __restrict__ hb,
                         const int* __restrict__ z, const float* __restrict__ emb) {
    int i = blockIdx.x * blockDim.x + threadIdx.x;
    if (i < Nn * 64) {
        int n = i >> 6, f = i & 63;
        float v = emb[z[n] * 64 + f];
        h[i] = v;
        hb[i] = (bf16)v;
    }
}

// ---------------- weight packing into MFMA A-fragment order ----------------
__device__ __forceinline__ void packfrag(bf16* dst, const float* src, int idx) {
    int j = idx & 7, lane = (idx >> 3) & 63, gT = idx >> 9;
    int kc = gT >> 2, T = gT & 3;
    int k = kc * 32 + (lane >> 4) * 8 + j;
    int n = T * 16 + (lane & 15);
    dst[idx] = (bf16)src[k * 64 + n];
}

__global__ void k_pack(const float* __restrict__ eW1, const float* __restrict__ eW2,
                       const float* __restrict__ nW1, const float* __restrict__ nW2,
                       const float* __restrict__ qW1,
                       bf16* __restrict__ pw1, bf16* __restrict__ pw2,
                       bf16* __restrict__ pn1, bf16* __restrict__ pn2,
                       bf16* __restrict__ pq1) {
    int tid = blockIdx.x * blockDim.x + threadIdx.x;
    if (tid < 32768) {
        int l = tid >> 13, idx = tid & 8191;
        packfrag(pw1 + l * 8192, eW1 + (size_t)l * 129 * 64, idx);
    } else if (tid < 49152) {
        int i = tid - 32768, l = i >> 12, idx = i & 4095;
        packfrag(pw2 + l * 4096, eW2 + (size_t)l * 4096, idx);
    } else if (tid < 81920) {
        int i = tid - 49152, l = i >> 13, idx = i & 8191;
        packfrag(pn1 + l * 8192, nW1 + (size_t)l * 8192, idx);
    } else if (tid < 98304) {
        int i = tid - 81920, l = i >> 12, idx = i & 4095;
        packfrag(pn2 + l * 4096, nW2 + (size_t)l * 4096, idx);
    } else if (tid < 102400) {
        packfrag(pq1, qW1, tid - 98304);
    }
}

// ---------------- CSR build ----------------
__global__ void k_hist(const int* __restrict__ rows, int* __restrict__ deg) {
    int e = blockIdx.x * blockDim.x + threadIdx.x;
    if (e < Ee) atomicAdd(&deg[rows[e]], 1);
}

__global__ void k_scan1(const int* __restrict__ deg, int* __restrict__ bsum) {
    __shared__ int red[4];
    int b = blockIdx.x;
    int i = b * 256 + threadIdx.x;
    int v = (i < Nn) ? deg[i] : 0;
#pragma unroll
    for (int off = 1; off < 64; off <<= 1) v += __shfl_xor(v, off);
    if ((threadIdx.x & 63) == 0) red[threadIdx.x >> 6] = v;
    __syncthreads();
    if (threadIdx.x == 0) bsum[b] = red[0] + red[1] + red[2] + red[3];
}

__global__ void k_scan2(const int* __restrict__ bsum, int* __restrict__ boff) {
    __shared__ int s[256];
    int t = threadIdx.x;
    int v = (t < NB) ? bsum[t] : 0;
    s[t] = v;
    __syncthreads();
    for (int off = 1; off < 256; off <<= 1) {
        int u = (t >= off) ? s[t - off] : 0;
        __syncthreads();
        s[t] += u;
        __syncthreads();
    }
    if (t < NB) boff[t] = s[t] - v;
}

// fused: exclusive scan -> cur (scatter cursor) + rows_s expansion
__global__ void k_scan3(const int* __restrict__ deg, const int* __restrict__ boff,
                        int* __restrict__ cur, int* __restrict__ rows_s) {
    __shared__ int s[256];
    int b = blockIdx.x, t = threadIdx.x;
    int i = b * 256 + t;
    int v = (i < Nn) ? deg[i] : 0;
    s[t] = v;
    __syncthreads();
    for (int off = 1; off < 256; off <<= 1) {
        int u = (t >= off) ? s[t - off] : 0;
        __syncthreads();
        s[t] += u;
        __syncthreads();
    }
    if (i < Nn) {
        int en = boff[b] + s[t];
        int st = en - v;
        cur[i] = st;
        for (int o = st; o < en; ++o) rows_s[o] = i;
    }
}

// cols-only scatter; cur holds absolute offsets
__global__ void k_scatter(const int* __restrict__ rows, const int* __restrict__ cols,
                          int* __restrict__ cur, int* __restrict__ cols_s) {
    int e = blockIdx.x * blockDim.x + threadIdx.x;
    if (e < Ee) {
        int o = atomicAdd(&cur[rows[e]], 1);
        cols_s[o] = cols[e];
    }
}

// ---------------- layer-0 node projection: Pa = H@W1a + b1, Pb = H@W1b (bf16 out) ----------------
__global__ __launch_bounds__(256) void k_proj(
    const bf16* __restrict__ hbuf, const bf16* __restrict__ pw1l,
    const float* __restrict__ b1v,
    bf16* __restrict__ Pa, bf16* __restrict__ Pb) {
    __shared__ __align__(16) bf16 inB[8 * 64 * 8];
    __shared__ float dhT[64 * 65];
    __shared__ __align__(16) float sb1[64];

    const int t = threadIdx.x;
    const int l = t & 63, w = t >> 6, q = l >> 4, nl = l & 15;
    const int fq = 4 * q;
    const int ge = t >> 2, part = t & 3;

    bf16x8 w1f[4][4];
#pragma unroll
    for (int kc = 0; kc < 4; ++kc)
#pragma unroll
        for (int T = 0; T < 4; ++T)
            w1f[kc][T] = *(const bf16x8*)(pw1l + (((kc * 4 + T) * 64 + l) << 3));
    if (t < 64) sb1[t] = b1v[t];

    const int NT = (Nn + 63) / 64;
    for (int bt = blockIdx.x; bt < NT; bt += gridDim.x) {
        const int base = bt * 64;
        __syncthreads();
        {
            int n = base + ge;
            if (n < Nn) {
                const bf16* hr = hbuf + ((size_t)n << 6) + part * 16;
                *(bf16x8*)&inB[(((part * 2 + 0) * 64) + ge) << 3] = *(const bf16x8*)(hr);
                *(bf16x8*)&inB[(((part * 2 + 1) * 64) + ge) << 3] = *(const bf16x8*)(hr + 8);
            } else {
                bf16x8 zz = {(bf16)0.f, (bf16)0.f, (bf16)0.f, (bf16)0.f,
                             (bf16)0.f, (bf16)0.f, (bf16)0.f, (bf16)0.f};
                *(bf16x8*)&inB[(((part * 2 + 0) * 64) + ge) << 3] = zz;
                *(bf16x8*)&inB[(((part * 2 + 1) * 64) + ge) << 3] = zz;
            }
        }
        __syncthreads();

        f32x4 apa[4], apb[4];
#pragma unroll
        for (int T = 0; T < 4; ++T) {
            apa[T] = (f32x4){0.f, 0.f, 0.f, 0.f};
            apb[T] = (f32x4){0.f, 0.f, 0.f, 0.f};
        }
#pragma unroll
        for (int kc = 0; kc < 2; ++kc) {
            bf16x8 bfrag = *(const bf16x8*)&inB[(((kc * 4 + q) * 64) + w * 16 + nl) << 3];
#pragma unroll
            for (int T = 0; T < 4; ++T) {
                apa[T] = __builtin_amdgcn_mfma_f32_16x16x32_bf16(w1f[kc][T], bfrag, apa[T], 0, 0, 0);
                apb[T] = __builtin_amdgcn_mfma_f32_16x16x32_bf16(w1f[kc + 2][T], bfrag, apb[T], 0, 0, 0);
            }
        }
#pragma unroll
        for (int T = 0; T < 4; ++T) {
#pragma unroll
            for (int r = 0; r < 4; ++r)
                dhT[(T * 16 + fq + r) * 65 + w * 16 + nl] = apa[T][r] + sb1[T * 16 + fq + r];
        }
        __syncthreads();
        {
            int n = base + ge;
            if (n < Nn) {
#pragma unroll
                for (int j = 0; j < 4; ++j) {
                    int f = part * 16 + j * 4;
                    bf16x4 bv = {(bf16)dhT[(f + 0) * 65 + ge], (bf16)dhT[(f + 1) * 65 + ge],
                                 (bf16)dhT[(f + 2) * 65 + ge], (bf16)dhT[(f + 3) * 65 + ge]};
                    *(bf16x4*)(Pa + ((size_t)n << 6) + f) = bv;
                }
            }
        }
        __syncthreads();
#pragma unroll
        for (int T = 0; T < 4; ++T) {
#pragma unroll
            for (int r = 0; r < 4; ++r)
                dhT[(T * 16 + fq + r) * 65 + w * 16 + nl] = apb[T][r];
        }
        __syncthreads();
        {
            int n = base + ge;
            if (n < Nn) {
#pragma unroll
                for (int j = 0; j < 4; ++j) {
                    int f = part * 16 + j * 4;
                    bf16x4 bv = {(bf16)dhT[(f + 0) * 65 + ge], (bf16)dhT[(f + 1) * 65 + ge],
                                 (bf16)dhT[(f + 2) * 65 + ge], (bf16)dhT[(f + 3) * 65 + ge]};
                    *(bf16x4*)(Pb + ((size_t)n << 6) + f) = bv;
                }
            }
        }
    }
}

// ---------------- edge kernel: gather bf16 Pa/Pb + rank-1 + silu -> GEMM2 only ----------------
__global__ __launch_bounds__(256, 8) void k_edge(
    const int* __restrict__ rows_s, const int* __restrict__ cols_s,
    const bf16* __restrict__ Pa, const bf16* __restrict__ Pb,
    const float* __restrict__ x,
    const bf16* __restrict__ pw2l,
    const float* __restrict__ w1f32,
    const float* __restrict__ b2v,
    const float* __restrict__ cwv, const float* __restrict__ cbv,
    float* __restrict__ m_agg, float* __restrict__ x_acc) {
    __shared__ __align__(16) bf16 lw2[4096];
    __shared__ __align__(16) float w128s[64], b2s[64], cws[64];
    __shared__ int mEp[32 * 65];
    __shared__ __align__(16) float relsm[64 * 4];
    __shared__ float coefs[64];
    __shared__ int srow[64];

    const int t = threadIdx.x;
    const int l = t & 63, w = t >> 6, q = l >> 4, nl = l & 15;
    const int fq = 4 * q;
    const int ge = l >> 2, part = l & 3;

    {
        const int4* s2 = (const int4*)pw2l;
        int4* d2p = (int4*)lw2;
#pragma unroll
        for (int i = 0; i < 2; ++i) d2p[t + 256 * i] = s2[t + 256 * i];
        if (t < 64) {
            w128s[t] = w1f32[128 * 64 + t];
            b2s[t] = b2v[t];
            cws[t] = cwv[t];
        }
    }
    const float cb0 = cbv[0];
    __syncthreads();

    for (int tile = blockIdx.x; tile < NTILES; tile += gridDim.x) {
        const int eo = tile * TE + w * 16;

        const int r_g = rows_s[eo + ge], c_g = cols_s[eo + ge];
        float rx = x[r_g * 3 + 0] - x[c_g * 3 + 0];
        float ry = x[r_g * 3 + 1] - x[c_g * 3 + 1];
        float rz = x[r_g * 3 + 2] - x[c_g * 3 + 2];
        float d2 = fmaf(rx, rx, fmaf(ry, ry, rz * rz));
        if (part == 0) {
            srow[w * 16 + ge] = r_g;
            float4 rv;
            rv.x = rx; rv.y = ry; rv.z = rz; rv.w = d2;
            *(float4*)&relsm[(w * 16 + ge) * 4] = rv;
        }

        const bf16* par = Pa + ((size_t)r_g << 6) + part * 16;
        const bf16* pbc = Pb + ((size_t)c_g << 6) + part * 16;
        int4 Ai = *(const int4*)(par);
        int4 Aj = *(const int4*)(par + 8);
        int4 Bi = *(const int4*)(pbc);
        int4 Bj = *(const int4*)(pbc + 8);
        const float4 w0 = *(const float4*)&w128s[part * 16 + 0];
        const float4 w1 = *(const float4*)&w128s[part * 16 + 4];
        const float4 w2q = *(const float4*)&w128s[part * 16 + 8];
        const float4 w3 = *(const float4*)&w128s[part * 16 + 12];

        int pk[8];
        pk[0] = pack2bf(silu_f(fmaf(w0.x, d2, unlo(Ai.x) + unlo(Bi.x))),
                        silu_f(fmaf(w0.y, d2, unhi(Ai.x) + unhi(Bi.x))));
        pk[1] = pack2bf(silu_f(fmaf(w0.z, d2, unlo(Ai.y) + unlo(Bi.y))),
                        silu_f(fmaf(w0.w, d2, unhi(Ai.y) + unhi(Bi.y))));
        pk[2] = pack2bf(silu_f(fmaf(w1.x, d2, unlo(Ai.z) + unlo(Bi.z))),
                        silu_f(fmaf(w1.y, d2, unhi(Ai.z) + unhi(Bi.z))));
        pk[3] = pack2bf(silu_f(fmaf(w1.z, d2, unlo(Ai.w) + unlo(Bi.w))),
                        silu_f(fmaf(w1.w, d2, unhi(Ai.w) + unhi(Bi.w))));
        pk[4] = pack2bf(silu_f(fmaf(w2q.x, d2, unlo(Aj.x) + unlo(Bj.x))),
                        silu_f(fmaf(w2q.y, d2, unhi(Aj.x) + unhi(Bj.x))));
        pk[5] = pack2bf(silu_f(fmaf(w2q.z, d2, unlo(Aj.y) + unlo(Bj.y))),
                        silu_f(fmaf(w2q.w, d2, unhi(Aj.y) + unhi(Bj.y))));
        pk[6] = pack2bf(silu_f(fmaf(w3.x, d2, unlo(Aj.z) + unlo(Bj.z))),
                        silu_f(fmaf(w3.y, d2, unhi(Aj.z) + unhi(Bj.z))));
        pk[7] = pack2bf(silu_f(fmaf(w3.z, d2, unlo(Aj.w) + unlo(Bj.w))),
                        silu_f(fmaf(w3.w, d2, unhi(Aj.w) + unhi(Bj.w))));

        f32x4 a2[4];
#pragma unroll
        for (int T = 0; T < 4; ++T) a2[T] = (f32x4){0.f, 0.f, 0.f, 0.f};
#pragma unroll
        for (int c2 = 0; c2 < 2; ++c2) {
            union { int i[4]; bf16x8 v; } bu;
            int src = nl * 4 + 2 * c2 + (q >> 1);
#pragma unroll
            for (int d = 0; d < 4; ++d) {
                int t0 = __shfl(pk[d], src);
                int t1 = __shfl(pk[4 + d], src);
                bu.i[d] = (q & 1) ? t1 : t0;
            }
#pragma unroll
            for (int T = 0; T < 4; ++T) {
                bf16x8 wf = *(const bf16x8*)&lw2[(((c2 * 4 + T) * 64) + l) << 3];
                a2[T] = __builtin_amdgcn_mfma_f32_16x16x32_bf16(wf, bu.v, a2[T], 0, 0, 0);
            }
        }
        float pc = 0.f;
#pragma unroll
        for (int T = 0; T < 4; ++T) {
            const float4 bq = *(const float4*)&b2s[T * 16 + fq];
            const float4 cq = *(const float4*)&cws[T * 16 + fq];
            float m0 = silu_f(a2[T][0] + bq.x);
            float m1 = silu_f(a2[T][1] + bq.y);
            float m2 = silu_f(a2[T][2] + bq.z);
            float m3 = silu_f(a2[T][3] + bq.w);
            int p0 = (T * 16 + fq) >> 1;
            mEp[(p0 + 0) * 65 + w * 16 + nl] = pack2bf(m0, m1);
            mEp[(p0 + 1) * 65 + w * 16 + nl] = pack2bf(m2, m3);
            pc += m0 * cq.x + m1 * cq.y + m2 * cq.z + m3 * cq.w;
        }
        pc += __shfl_xor(pc, 16);
        pc += __shfl_xor(pc, 32);
        if (q == 0) coefs[w * 16 + nl] = tanh_f(pc + cb0);
        __syncthreads();  // barrier A

        {
            int rl = srow[l];
            int rprev = __shfl(rl, l - 1);
            bool isst = (l == 0) || (rl != rprev);
            unsigned long long mask = __ballot(isst);
            const int pair = l & 31, half = l >> 5;
            unsigned long long mm = mask;
            int s = 0;
            while (mm) {
                int st = __ffsll(mm) - 1;
                mm &= mm - 1;
                if ((s & 3) == w) {
                    int en = mm ? (__ffsll(mm) - 1) : TE;
                    int row = __shfl(rl, st);
                    float s0 = 0.f, s1 = 0.f, sx = 0.f;
                    for (int e = st + half; e < en; e += 2) {
                        int pv = mEp[pair * 65 + e];
                        s0 += __builtin_bit_cast(float, pv << 16);
                        s1 += __builtin_bit_cast(float, pv & 0xffff0000);
                    }
                    if (half == 1 && pair < 3) {
                        for (int e = st; e < en; ++e)
                            sx += relsm[e * 4 + pair] * coefs[e];
                    }
                    s0 += __shfl_xor(s0, 32);
                    s1 += __shfl_xor(s1, 32);
                    if (half == 0) {
                        atomicAdd(m_agg + (size_t)row * 64 + 2 * pair, s0);
                        atomicAdd(m_agg + (size_t)row * 64 + 2 * pair + 1, s1);
                    } else if (pair < 3) {
                        atomicAdd(x_acc + (size_t)row * 3 + pair, sx);
                    }
                }
                s++;
            }
        }
        __syncthreads();  // barrier B
    }
}

// ---------------- node kernel (MFMA, grid-stride; fused next-layer projection; zeroes accumulators) ----------------
__global__ __launch_bounds__(256) void k_node(
    float* __restrict__ m_agg, float* __restrict__ x_acc,
    const bf16* __restrict__ pn1l, const bf16* __restrict__ pn2l,
    const float* __restrict__ b1v, const float* __restrict__ b2v,
    float* __restrict__ h, bf16* __restrict__ hbuf, float* __restrict__ x,
    const bf16* __restrict__ pw1n, const float* __restrict__ b1n,
    bf16* __restrict__ Pa, bf16* __restrict__ Pb, int donext) {
    __shared__ __align__(16) bf16 inB[16 * 64 * 8];
    __shared__ float dhT[64 * 65];
    __shared__ __align__(16) float sb1[64], sb2[64], sb1n[64];

    const int t = threadIdx.x;
    const int l = t & 63, w = t >> 6, q = l >> 4, nl = l & 15;
    const int qh = q >> 1, qb = 2 * (q & 1), fq = 4 * q;
    const int ge = t >> 2, part = t & 3;

    bf16x8 w1f[4][4];
#pragma unroll
    for (int kc = 0; kc < 4; ++kc)
#pragma unroll
        for (int T = 0; T < 4; ++T)
            w1f[kc][T] = *(const bf16x8*)(pn1l + (((kc * 4 + T) * 64 + l) << 3));
    bf16x8 w2f[2][4];
#pragma unroll
    for (int c = 0; c < 2; ++c)
#pragma unroll
        for (int T = 0; T < 4; ++T)
            w2f[c][T] = *(const bf16x8*)(pn2l + (((c * 4 + T) * 64 + l) << 3));
    if (t < 64) { sb1[t] = b1v[t]; sb2[t] = b2v[t]; sb1n[t] = b1n[t]; }

    const int NT = (Nn + 63) / 64;
    for (int bt = blockIdx.x; bt < NT; bt += gridDim.x) {
        const int base = bt * 64;
        const int n_g = base + ge;
        __syncthreads();
        {
            if (n_g < Nn) {
                const bf16* hr = hbuf + ((size_t)n_g << 6) + part * 16;
                *(bf16x8*)&inB[(((part * 2 + 0) * 64) + ge) << 3] = *(const bf16x8*)(hr);
                *(bf16x8*)&inB[(((part * 2 + 1) * 64) + ge) << 3] = *(const bf16x8*)(hr + 8);
                float* mr = m_agg + ((size_t)n_g << 6) + part * 16;
                float4 m0 = *(const float4*)(mr + 0);
                float4 m1 = *(const float4*)(mr + 4);
                float4 m2 = *(const float4*)(mr + 8);
                float4 m3 = *(const float4*)(mr + 12);
                // zero accumulators for next layer (replaces hipMemsetAsync)
                float4 z4 = {0.f, 0.f, 0.f, 0.f};
                *(float4*)(mr + 0) = z4;
                *(float4*)(mr + 4) = z4;
                *(float4*)(mr + 8) = z4;
                *(float4*)(mr + 12) = z4;
                bf16x8 bm0 = {(bf16)m0.x, (bf16)m0.y, (bf16)m0.z, (bf16)m0.w,
                              (bf16)m1.x, (bf16)m1.y, (bf16)m1.z, (bf16)m1.w};
                bf16x8 bm1 = {(bf16)m2.x, (bf16)m2.y, (bf16)m2.z, (bf16)m2.w,
                              (bf16)m3.x, (bf16)m3.y, (bf16)m3.z, (bf16)m3.w};
                *(bf16x8*)&inB[(((8 + part * 2 + 0) * 64) + ge) << 3] = bm0;
                *(bf16x8*)&inB[(((8 + part * 2 + 1) * 64) + ge) << 3] = bm1;
            } else {
                bf16x8 zz = {(bf16)0.f, (bf16)0.f, (bf16)0.f, (bf16)0.f,
                             (bf16)0.f, (bf16)0.f, (bf16)0.f, (bf16)0.f};
                *(bf16x8*)&inB[(((part * 2 + 0) * 64) + ge) << 3] = zz;
                *(bf16x8*)&inB[(((part * 2 + 1) * 64) + ge) << 3] = zz;
                *(bf16x8*)&inB[(((8 + part * 2 + 0) * 64) + ge) << 3] = zz;
                *(bf16x8*)&inB[(((8 + part * 2 + 1) * 64) + ge) << 3] = zz;
            }
        }
        __syncthreads();

        f32x4 a1[4];
#pragma unroll
        for (int T = 0; T < 4; ++T) a1[T] = (f32x4){0.f, 0.f, 0.f, 0.f};
#pragma unroll
        for (int kc = 0; kc < 4; ++kc) {
            bf16x8 bfrag = *(const bf16x8*)&inB[(((kc * 4 + q) * 64) + w * 16 + nl) << 3];
#pragma unroll
            for (int T = 0; T < 4; ++T)
                a1[T] = __builtin_amdgcn_mfma_f32_16x16x32_bf16(w1f[kc][T], bfrag, a1[T], 0, 0, 0);
        }
        int pk[4][2];
#pragma unroll
        for (int T = 0; T < 4; ++T) {
            const float4 bq = *(const float4*)&sb1[T * 16 + fq];
            float h0 = silu_f(a1[T][0] + bq.x);
            float h1 = silu_f(a1[T][1] + bq.y);
            float h2 = silu_f(a1[T][2] + bq.z);
            float h3 = silu_f(a1[T][3] + bq.w);
            pk[T][0] = pack2bf(h0, h1);
            pk[T][1] = pack2bf(h2, h3);
        }
        f32x4 a2[4];
#pragma unroll
        for (int T = 0; T < 4; ++T) a2[T] = (f32x4){0.f, 0.f, 0.f, 0.f};
#pragma unroll
        for (int c = 0; c < 2; ++c) {
            union { int i[4]; bf16x8 v; } bu;
#pragma unroll
            for (int d = 0; d < 4; ++d) {
                int src = (qb + (d >> 1)) * 16 + nl;
                int t0 = __shfl(pk[2 * c][d & 1], src);
                int t1 = __shfl(pk[2 * c + 1][d & 1], src);
                bu.i[d] = qh ? t1 : t0;
            }
#pragma unroll
            for (int T = 0; T < 4; ++T)
                a2[T] = __builtin_amdgcn_mfma_f32_16x16x32_bf16(w2f[c][T], bu.v, a2[T], 0, 0, 0);
        }
#pragma unroll
        for (int T = 0; T < 4; ++T) {
            const float4 bq = *(const float4*)&sb2[T * 16 + fq];
            dhT[(T * 16 + fq + 0) * 65 + w * 16 + nl] = a2[T][0] + bq.x;
            dhT[(T * 16 + fq + 1) * 65 + w * 16 + nl] = a2[T][1] + bq.y;
            dhT[(T * 16 + fq + 2) * 65 + w * 16 + nl] = a2[T][2] + bq.z;
            dhT[(T * 16 + fq + 3) * 65 + w * 16 + nl] = a2[T][3] + bq.w;
        }
        __syncthreads();
        {
            if (n_g < Nn) {
                bf16x4 hv[4];
#pragma unroll
                for (int j = 0; j < 4; ++j) {
                    int f = part * 16 + j * 4;
                    float4* hp = (float4*)(h + ((size_t)n_g << 6) + f);
                    float4 old = *hp;
                    old.x += dhT[(f + 0) * 65 + ge];
                    old.y += dhT[(f + 1) * 65 + ge];
                    old.z += dhT[(f + 2) * 65 + ge];
                    old.w += dhT[(f + 3) * 65 + ge];
                    *hp = old;
                    hv[j] = (bf16x4){(bf16)old.x, (bf16)old.y, (bf16)old.z, (bf16)old.w};
                    *(bf16x4*)(hbuf + ((size_t)n_g << 6) + f) = hv[j];
                }
                if (donext) {
                    union { bf16x4 h2[2]; bf16x8 v; } u0, u1;
                    u0.h2[0] = hv[0]; u0.h2[1] = hv[1];
                    u1.h2[0] = hv[2]; u1.h2[1] = hv[3];
                    *(bf16x8*)&inB[(((part * 2 + 0) * 64) + ge) << 3] = u0.v;
                    *(bf16x8*)&inB[(((part * 2 + 1) * 64) + ge) << 3] = u1.v;
                }
            } else if (donext) {
                bf16x8 zz = {(bf16)0.f, (bf16)0.f, (bf16)0.f, (bf16)0.f,
                             (bf16)0.f, (bf16)0.f, (bf16)0.f, (bf16)0.f};
                *(bf16x8*)&inB[(((part * 2 + 0) * 64) + ge) << 3] = zz;
                *(bf16x8*)&inB[(((part * 2 + 1) * 64) + ge) << 3] = zz;
            }
        }
        if (t < 64) {
            int n = base + t;
            if (n < Nn) {
#pragma unroll
                for (int c = 0; c < 3; ++c) {
                    x[n * 3 + c] += x_acc[n * 3 + c];
                    x_acc[n * 3 + c] = 0.f;  // zero for next layer
                }
            }
        }
        if (!donext) continue;
        __syncthreads();
        f32x4 apa[4], apb[4];
#pragma unroll
        for (int T = 0; T < 4; ++T) {
            apa[T] = (f32x4){0.f, 0.f, 0.f, 0.f};
            apb[T] = (f32x4){0.f, 0.f, 0.f, 0.f};
        }
#pragma unroll
        for (int kc = 0; kc < 2; ++kc) {
            bf16x8 bfrag = *(const bf16x8*)&inB[(((kc * 4 + q) * 64) + w * 16 + nl) << 3];
#pragma unroll
            for (int T = 0; T < 4; ++T) {
                bf16x8 wa = *(const bf16x8*)(pw1n + (((kc * 4 + T) * 64 + l) << 3));
                bf16x8 wb = *(const bf16x8*)(pw1n + ((((kc + 2) * 4 + T) * 64 + l) << 3));
                apa[T] = __builtin_amdgcn_mfma_f32_16x16x32_bf16(wa, bfrag, apa[T], 0, 0, 0);
                apb[T] = __builtin_amdgcn_mfma_f32_16x16x32_bf16(wb, bfrag, apb[T], 0, 0, 0);
            }
        }
#pragma unroll
        for (int T = 0; T < 4; ++T) {
#pragma unroll
            for (int r = 0; r < 4; ++r)
                dhT[(T * 16 + fq + r) * 65 + w * 16 + nl] = apa[T][r] + sb1n[T * 16 + fq + r];
        }
        __syncthreads();
        if (n_g < Nn) {
#pragma unroll
            for (int j = 0; j < 4; ++j) {
                int f = part * 16 + j * 4;
                bf16x4 bv = {(bf16)dhT[(f + 0) * 65 + ge], (bf16)dhT[(f + 1) * 65 + ge],
                             (bf16)dhT[(f + 2) * 65 + ge], (bf16)dhT[(f + 3) * 65 + ge]};
                *(bf16x4*)(Pa + ((size_t)n_g << 6) + f) = bv;
            }
        }
        __syncthreads();
#pragma unroll
        for (int T = 0; T < 4; ++T) {
#pragma unroll
            for (int r = 0; r < 4; ++r)
                dhT[(T * 16 + fq + r) * 65 + w * 16 + nl] = apb[T][r];
        }
        __syncthreads();
        if (n_g < Nn) {
#pragma unroll
            for (int j = 0; j < 4; ++j) {
                int f = part * 16 + j * 4;
                bf16x4 bv = {(bf16)dhT[(f + 0) * 65 + ge], (bf16)dhT[(f + 1) * 65 + ge],
                             (bf16)dhT[(f + 2) * 65 + ge], (bf16)dhT[(f + 3) * 65 + ge]};
                *(bf16x4*)(Pb + ((size_t)n_g << 6) + f) = bv;
            }
        }
    }
}

// ---------------- readout q (MFMA) + batch stats fused ----------------
__global__ __launch_bounds__(256) void k_q(
    const bf16* __restrict__ hbuf, const bf16* __restrict__ pq1,
    const float* __restrict__ b1v, const float* __restrict__ w2v,
    const float* __restrict__ b2v, float* __restrict__ qout,
    const int* __restrict__ batch, const float* __restrict__ x,
    float* __restrict__ cnt, float* __restrict__ xs) {
    __shared__ __align__(16) bf16 inB[8 * 64 * 8];
    __shared__ __align__(16) float sb1[64], sw2[64];
    const int t = threadIdx.x;
    const int l = t & 63, w = t >> 6, q = l >> 4, nl = l & 15;
    const int fq = 4 * q;
    const int ge = t >> 2, part = t & 3;

    bf16x8 w1f[2][4];
#pragma unroll
    for (int kc = 0; kc < 2; ++kc)
#pragma unroll
        for (int T = 0; T < 4; ++T)
            w1f[kc][T] = *(const bf16x8*)(pq1 + (((kc * 4 + T) * 64 + l) << 3));
    if (t < 64) { sb1[t] = b1v[t]; sw2[t] = w2v[t]; }
    const float qb2 = b2v[0];

    const int base = blockIdx.x * 64;
    // fused batch stats (independent of q computation)
    if (t < 64) {
        int n = base + t;
        if (n < Nn) {
            int b = batch[n];
            atomicAdd(&cnt[b], 1.f);
            atomicAdd(&xs[b * 3 + 0], x[n * 3 + 0]);
            atomicAdd(&xs[b * 3 + 1], x[n * 3 + 1]);
            atomicAdd(&xs[b * 3 + 2], x[n * 3 + 2]);
        }
    }
    {
        int n = base + ge;
        if (n < Nn) {
            const bf16* hr = hbuf + ((size_t)n << 6) + part * 16;
            *(bf16x8*)&inB[(((part * 2 + 0) * 64) + ge) << 3] = *(const bf16x8*)(hr);
            *(bf16x8*)&inB[(((part * 2 + 1) * 64) + ge) << 3] = *(const bf16x8*)(hr + 8);
        } else {
            bf16x8 zz = {(bf16)0.f, (bf16)0.f, (bf16)0.f, (bf16)0.f,
                         (bf16)0.f, (bf16)0.f, (bf16)0.f, (bf16)0.f};
            *(bf16x8*)&inB[(((part * 2 + 0) * 64) + ge) << 3] = zz;
            *(bf16x8*)&inB[(((part * 2 + 1) * 64) + ge) << 3] = zz;
        }
    }
    __syncthreads();
    f32x4 a1[4];
#pragma unroll
    for (int T = 0; T < 4; ++T) a1[T] = (f32x4){0.f, 0.f, 0.f, 0.f};
#pragma unroll
    for (int kc = 0; kc < 2; ++kc) {
        bf16x8 bfrag = *(const bf16x8*)&inB[(((kc * 4 + q) * 64) + w * 16 + nl) << 3];
#pragma unroll
        for (int T = 0; T < 4; ++T)
            a1[T] = __builtin_amdgcn_mfma_f32_16x16x32_bf16(w1f[kc][T], bfrag, a1[T], 0, 0, 0);
    }
    float pc = 0.f;
#pragma unroll
    for (int T = 0; T < 4; ++T) {
        const float4 bq = *(const float4*)&sb1[T * 16 + fq];
        const float4 cq = *(const float4*)&sw2[T * 16 + fq];
        pc += silu_f(a1[T][0] + bq.x) * cq.x;
        pc += silu_f(a1[T][1] + bq.y) * cq.y;
        pc += silu_f(a1[T][2] + bq.z) * cq.z;
        pc += silu_f(a1[T][3] + bq.w) * cq.w;
    }
    pc += __shfl_xor(pc, 16);
    pc += __shfl_xor(pc, 32);
    if (q == 0) {
        int n = base + w * 16 + nl;
        if (n < Nn) qout[n] = pc + qb2;
    }
}

__global__ void k_mu(const int* __restrict__ batch, const float* __restrict__ x,
                     const float* __restrict__ q, const float* __restrict__ cnt,
                     const float* __restrict__ xs, float* __restrict__ out) {
    int n = blockIdx.x * blockDim.x + threadIdx.x;
    if (n < Nn) {
        int b = batch[n];
        float cc = fmaxf(cnt[b], 1.f);
        float qn = q[n];
#pragma unroll
        for (int c = 0; c < 3; ++c) {
            float xr = x[n * 3 + c] - xs[b * 3 + c] / cc;
            atomicAdd(&out[b * 3 + c], qn * xr);
        }
    }
}

// ---------------- launch ----------------
extern "C" void kernel_launch(void* const* d_in, const int* in_sizes, int n_in,
                              void* d_out, int out_size, void* d_ws, size_t ws_size,
                              hipStream_t stream) {
    const int* z = (const int*)d_in[0];
    const float* pos = (const float*)d_in[1];
    const int* ei0 = (const int*)d_in[2];
    const int* ei1 = ei0 + Ee;
    const int* batch = (const int*)d_in[3];
    const float* emb = (const float*)d_in[4];
    const float* eW1 = (const float*)d_in[5];
    const float* eb1 = (const float*)d_in[6];
    const float* eW2 = (const float*)d_in[7];
    const float* eb2 = (const float*)d_in[8];
    const float* cW = (const float*)d_in[9];
    const float* cb = (const float*)d_in[10];
    const float* nW1 = (const float*)d_in[11];
    const float* nb1 = (const float*)d_in[12];
    const float* nW2 = (const float*)d_in[13];
    const float* nb2 = (const float*)d_in[14];
    const float* qW1 = (const float*)d_in[15];
    const float* qb1 = (const float*)d_in[16];
    const float* qW2 = (const float*)d_in[17];
    const float* qb2 = (const float*)d_in[18];

    char* ws = (char*)d_ws;
    size_t o = 0;
    auto alloc = [&](size_t bytes) {
        size_t r = o;
        o = (o + bytes + 255) & ~(size_t)255;
        return r;
    };
    float* h = (float*)(ws + alloc((size_t)Nn * 64 * 4));
    float* xp = (float*)(ws + alloc((size_t)Nn * 3 * 4));
    float* magg = (float*)(ws + alloc((size_t)Nn * 64 * 4));
    float* xacc = (float*)(ws + alloc((size_t)Nn * 3 * 4));
    size_t zero_span = (size_t)((char*)xacc - (char*)magg) + (size_t)Nn * 3 * 4;
    float* qv = (float*)(ws + alloc((size_t)Nn * 4));
    int* deg = (int*)(ws + alloc((size_t)Nn * 4));
    int* cur = (int*)(ws + alloc((size_t)Nn * 4));
    int* rows_s = (int*)(ws + alloc((size_t)Ee * 4));
    int* cols_s = (int*)(ws + alloc((size_t)Ee * 4));
    float* cnt = (float*)(ws + alloc((size_t)Bb * 4));
    float* xs = (float*)(ws + alloc((size_t)Bb * 3 * 4));
    bf16* hbm = (bf16*)(ws + alloc((size_t)Nn * 64 * 2));
    bf16* Pa = (bf16*)(ws + alloc((size_t)Nn * 64 * 2));
    bf16* Pb = (bf16*)(ws + alloc((size_t)Nn * 64 * 2));
    bf16* pw1 = (bf16*)(ws + alloc((size_t)4 * 8192 * 2));
    bf16* pw2 = (bf16*)(ws + alloc((size_t)4 * 4096 * 2));
    bf16* pn1 = (bf16*)(ws + alloc((size_t)4 * 8192 * 2));
    bf16* pn2 = (bf16*)(ws + alloc((size_t)4 * 4096 * 2));
    bf16* pq1 = (bf16*)(ws + alloc((size_t)4096 * 2));
    int* bsum = (int*)(ws + alloc((size_t)NB * 4));
    int* boff = (int*)(ws + alloc((size_t)NB * 4));

    hipMemsetAsync(deg, 0, (size_t)Nn * 4, stream);
    hipMemsetAsync(magg, 0, zero_span, stream);   // layers 1..3 zeroed by k_node
    hipMemsetAsync(cnt, 0, (size_t)Bb * 4, stream);
    hipMemsetAsync(xs, 0, (size_t)Bb * 3 * 4, stream);
    hipMemsetAsync(d_out, 0, (size_t)out_size * 4, stream);

    k_init_h<<<(Nn * 64 + 255) / 256, 256, 0, stream>>>(h, hbm, z, emb);
    hipMemcpyAsync(xp, pos, (size_t)Nn * 3 * 4, hipMemcpyDeviceToDevice, stream);
    k_pack<<<(102400 + 255) / 256, 256, 0, stream>>>(eW1, eW2, nW1, nW2, qW1,
                                                     pw1, pw2, pn1, pn2, pq1);
    k_hist<<<(Ee + 255) / 256, 256, 0, stream>>>(ei0, deg);
    k_scan1<<<NB, 256, 0, stream>>>(deg, bsum);
    k_scan2<<<1, 256, 0, stream>>>(bsum, boff);
    k_scan3<<<NB, 256, 0, stream>>>(deg, boff, cur, rows_s);
    k_scatter<<<(Ee + 255) / 256, 256, 0, stream>>>(ei0, ei1, cur, cols_s);

    k_proj<<<256, 256, 0, stream>>>(hbm, pw1, eb1, Pa, Pb);
    for (int l = 0; l < 4; ++l) {
        k_edge<<<2048, 256, 0, stream>>>(rows_s, cols_s, Pa, Pb, xp,
                                         pw2 + (size_t)l * 4096,
                                         eW1 + (size_t)l * 129 * 64,
                                         eb2 + l * 64,
                                         cW + l * 64, cb + l, magg, xacc);
        int nx = (l < 3) ? (l + 1) : 0;
        k_node<<<256, 256, 0, stream>>>(magg, xacc,
                                        pn1 + (size_t)l * 8192, pn2 + (size_t)l * 4096,
                                        nb1 + l * 64, nb2 + l * 64,
                                        h, hbm, xp,
                                        pw1 + (size_t)nx * 8192, eb1 + nx * 64,
                                        Pa, Pb, (l < 3) ? 1 : 0);
    }
    k_q<<<(Nn + 63) / 64, 256, 0, stream>>>(hbm, pq1, qb1, qW2, qb2, qv,
                                            batch, xp, cnt, xs);
    k_mu<<<(Nn + 255) / 256, 256, 0, stream>>>(batch, xp, qv, cnt, xs, (float*)d_out);
}

// Round 19
// 1005.594 us; speedup vs baseline: 1.0494x; 1.0256x over previous
//
#include <hip/hip_runtime.h>
#include <math.h>

#define Nn 50000
#define Ee 1600000
#define Bb 512
#define TE 64
#define NTILES (Ee / TE)
#define NB ((Nn + 255) / 256)

typedef __bf16 bf16;
typedef __bf16 bf16x8 __attribute__((ext_vector_type(8)));
typedef __bf16 bf16x4 __attribute__((ext_vector_type(4)));
typedef float f32x4 __attribute__((ext_vector_type(4)));

__device__ __forceinline__ float silu_f(float v) {
    return v * __builtin_amdgcn_rcpf(1.f + __expf(-v));
}
__device__ __forceinline__ float tanh_f(float x) {
    float e = __expf(2.f * x);
    return 1.f - 2.f * __builtin_amdgcn_rcpf(e + 1.f);
}
__device__ __forceinline__ int pack2bf(float a, float b) {
    unsigned short ua = __builtin_bit_cast(unsigned short, (bf16)a);
    unsigned short ub = __builtin_bit_cast(unsigned short, (bf16)b);
    return (int)ua | ((int)ub << 16);
}
__device__ __forceinline__ float unlo(int v) {
    return __builtin_bit_cast(float, v << 16);
}
__device__ __forceinline__ float unhi(int v) {
    return __builtin_bit_cast(float, v & 0xffff0000);
}

// ---------------- init: h = emb[z] (fp32 + bf16 mirror) ----------------
__global__ void k_init_h(float* __restrict__ h, bf16* __restrict__ hb,
                         const int* __restrict__ z, const float* __restrict__ emb) {
    int i = blockIdx.x * blockDim.x + threadIdx.x;
    if (i < Nn * 64) {
        int n = i >> 6, f = i & 63;
        float v = emb[z[n] * 64 + f];
        h[i] = v;
        hb[i] = (bf16)v;
    }
}

// ---------------- weight packing into MFMA A-fragment order ----------------
__device__ __forceinline__ void packfrag(bf16* dst, const float* src, int idx) {
    int j = idx & 7, lane = (idx >> 3) & 63, gT = idx >> 9;
    int kc = gT >> 2, T = gT & 3;
    int k = kc * 32 + (lane >> 4) * 8 + j;
    int n = T * 16 + (lane & 15);
    dst[idx] = (bf16)src[k * 64 + n];
}

__global__ void k_pack(const float* __restrict__ eW1, const float* __restrict__ eW2,
                       const float* __restrict__ nW1, const float* __restrict__ nW2,
                       const float* __restrict__ qW1,
                       bf16* __restrict__ pw1, bf16* __restrict__ pw2,
                       bf16* __restrict__ pn1, bf16* __restrict__ pn2,
                       bf16* __restrict__ pq1) {
    int tid = blockIdx.x * blockDim.x + threadIdx.x;
    if (tid < 32768) {
        int l = tid >> 13, idx = tid & 8191;
        packfrag(pw1 + l * 8192, eW1 + (size_t)l * 129 * 64, idx);
    } else if (tid < 49152) {
        int i = tid - 32768, l = i >> 12, idx = i & 4095;
        packfrag(pw2 + l * 4096, eW2 + (size_t)l * 4096, idx);
    } else if (tid < 81920) {
        int i = tid - 49152, l = i >> 13, idx = i & 8191;
        packfrag(pn1 + l * 8192, nW1 + (size_t)l * 8192, idx);
    } else if (tid < 98304) {
        int i = tid - 81920, l = i >> 12, idx = i & 4095;
        packfrag(pn2 + l * 4096, nW2 + (size_t)l * 4096, idx);
    } else if (tid < 102400) {
        packfrag(pq1, qW1, tid - 98304);
    }
}

// ---------------- CSR build ----------------
__global__ void k_hist(const int* __restrict__ rows, int* __restrict__ deg) {
    int e = blockIdx.x * blockDim.x + threadIdx.x;
    if (e < Ee) atomicAdd(&deg[rows[e]], 1);
}

__global__ void k_scan1(const int* __restrict__ deg, int* __restrict__ bsum) {
    __shared__ int red[4];
    int b = blockIdx.x;
    int i = b * 256 + threadIdx.x;
    int v = (i < Nn) ? deg[i] : 0;
#pragma unroll
    for (int off = 1; off < 64; off <<= 1) v += __shfl_xor(v, off);
    if ((threadIdx.x & 63) == 0) red[threadIdx.x >> 6] = v;
    __syncthreads();
    if (threadIdx.x == 0) bsum[b] = red[0] + red[1] + red[2] + red[3];
}

__global__ void k_scan2(const int* __restrict__ bsum, int* __restrict__ boff) {
    __shared__ int s[256];
    int t = threadIdx.x;
    int v = (t < NB) ? bsum[t] : 0;
    s[t] = v;
    __syncthreads();
    for (int off = 1; off < 256; off <<= 1) {
        int u = (t >= off) ? s[t - off] : 0;
        __syncthreads();
        s[t] += u;
        __syncthreads();
    }
    if (t < NB) boff[t] = s[t] - v;
}

// fused: exclusive scan -> cur (scatter cursor) + rows_s expansion
__global__ void k_scan3(const int* __restrict__ deg, const int* __restrict__ boff,
                        int* __restrict__ cur, int* __restrict__ rows_s) {
    __shared__ int s[256];
    int b = blockIdx.x, t = threadIdx.x;
    int i = b * 256 + t;
    int v = (i < Nn) ? deg[i] : 0;
    s[t] = v;
    __syncthreads();
    for (int off = 1; off < 256; off <<= 1) {
        int u = (t >= off) ? s[t - off] : 0;
        __syncthreads();
        s[t] += u;
        __syncthreads();
    }
    if (i < Nn) {
        int en = boff[b] + s[t];
        int st = en - v;
        cur[i] = st;
        for (int o = st; o < en; ++o) rows_s[o] = i;
    }
}

// cols-only scatter; cur holds absolute offsets
__global__ void k_scatter(const int* __restrict__ rows, const int* __restrict__ cols,
                          int* __restrict__ cur, int* __restrict__ cols_s) {
    int e = blockIdx.x * blockDim.x + threadIdx.x;
    if (e < Ee) {
        int o = atomicAdd(&cur[rows[e]], 1);
        cols_s[o] = cols[e];
    }
}

// ---------------- layer-0 node projection: Pa = H@W1a + b1, Pb = H@W1b (bf16 out) ----------------
__global__ __launch_bounds__(256) void k_proj(
    const bf16* __restrict__ hbuf, const bf16* __restrict__ pw1l,
    const float* __restrict__ b1v,
    bf16* __restrict__ Pa, bf16* __restrict__ Pb) {
    __shared__ __align__(16) bf16 inB[8 * 64 * 8];
    __shared__ float dhT[64 * 65];
    __shared__ __align__(16) float sb1[64];

    const int t = threadIdx.x;
    const int l = t & 63, w = t >> 6, q = l >> 4, nl = l & 15;
    const int fq = 4 * q;
    const int ge = t >> 2, part = t & 3;

    bf16x8 w1f[4][4];
#pragma unroll
    for (int kc = 0; kc < 4; ++kc)
#pragma unroll
        for (int T = 0; T < 4; ++T)
            w1f[kc][T] = *(const bf16x8*)(pw1l + (((kc * 4 + T) * 64 + l) << 3));
    if (t < 64) sb1[t] = b1v[t];

    const int NT = (Nn + 63) / 64;
    for (int bt = blockIdx.x; bt < NT; bt += gridDim.x) {
        const int base = bt * 64;
        __syncthreads();
        {
            int n = base + ge;
            if (n < Nn) {
                const bf16* hr = hbuf + ((size_t)n << 6) + part * 16;
                *(bf16x8*)&inB[(((part * 2 + 0) * 64) + ge) << 3] = *(const bf16x8*)(hr);
                *(bf16x8*)&inB[(((part * 2 + 1) * 64) + ge) << 3] = *(const bf16x8*)(hr + 8);
            } else {
                bf16x8 zz = {(bf16)0.f, (bf16)0.f, (bf16)0.f, (bf16)0.f,
                             (bf16)0.f, (bf16)0.f, (bf16)0.f, (bf16)0.f};
                *(bf16x8*)&inB[(((part * 2 + 0) * 64) + ge) << 3] = zz;
                *(bf16x8*)&inB[(((part * 2 + 1) * 64) + ge) << 3] = zz;
            }
        }
        __syncthreads();

        f32x4 apa[4], apb[4];
#pragma unroll
        for (int T = 0; T < 4; ++T) {
            apa[T] = (f32x4){0.f, 0.f, 0.f, 0.f};
            apb[T] = (f32x4){0.f, 0.f, 0.f, 0.f};
        }
#pragma unroll
        for (int kc = 0; kc < 2; ++kc) {
            bf16x8 bfrag = *(const bf16x8*)&inB[(((kc * 4 + q) * 64) + w * 16 + nl) << 3];
#pragma unroll
            for (int T = 0; T < 4; ++T) {
                apa[T] = __builtin_amdgcn_mfma_f32_16x16x32_bf16(w1f[kc][T], bfrag, apa[T], 0, 0, 0);
                apb[T] = __builtin_amdgcn_mfma_f32_16x16x32_bf16(w1f[kc + 2][T], bfrag, apb[T], 0, 0, 0);
            }
        }
#pragma unroll
        for (int T = 0; T < 4; ++T) {
#pragma unroll
            for (int r = 0; r < 4; ++r)
                dhT[(T * 16 + fq + r) * 65 + w * 16 + nl] = apa[T][r] + sb1[T * 16 + fq + r];
        }
        __syncthreads();
        {
            int n = base + ge;
            if (n < Nn) {
#pragma unroll
                for (int j = 0; j < 4; ++j) {
                    int f = part * 16 + j * 4;
                    bf16x4 bv = {(bf16)dhT[(f + 0) * 65 + ge], (bf16)dhT[(f + 1) * 65 + ge],
                                 (bf16)dhT[(f + 2) * 65 + ge], (bf16)dhT[(f + 3) * 65 + ge]};
                    *(bf16x4*)(Pa + ((size_t)n << 6) + f) = bv;
                }
            }
        }
        __syncthreads();
#pragma unroll
        for (int T = 0; T < 4; ++T) {
#pragma unroll
            for (int r = 0; r < 4; ++r)
                dhT[(T * 16 + fq + r) * 65 + w * 16 + nl] = apb[T][r];
        }
        __syncthreads();
        {
            int n = base + ge;
            if (n < Nn) {
#pragma unroll
                for (int j = 0; j < 4; ++j) {
                    int f = part * 16 + j * 4;
                    bf16x4 bv = {(bf16)dhT[(f + 0) * 65 + ge], (bf16)dhT[(f + 1) * 65 + ge],
                                 (bf16)dhT[(f + 2) * 65 + ge], (bf16)dhT[(f + 3) * 65 + ge]};
                    *(bf16x4*)(Pb + ((size_t)n << 6) + f) = bv;
                }
            }
        }
    }
}

// ---------------- edge kernel: gather bf16 Pa/Pb + rank-1 + silu -> GEMM2 only ----------------
__global__ __launch_bounds__(256, 8) void k_edge(
    const int* __restrict__ rows_s, const int* __restrict__ cols_s,
    const bf16* __restrict__ Pa, const bf16* __restrict__ Pb,
    const float* __restrict__ x,
    const bf16* __restrict__ pw2l,
    const float* __restrict__ w1f32,
    const float* __restrict__ b2v,
    const float* __restrict__ cwv, const float* __restrict__ cbv,
    float* __restrict__ m_agg, float* __restrict__ x_acc) {
    __shared__ __align__(16) bf16 lw2[4096];
    __shared__ __align__(16) float w128s[64], b2s[64], cws[64];
    __shared__ int mEp[32 * 65];
    __shared__ __align__(16) float relsm[64 * 4];
    __shared__ float coefs[64];
    __shared__ int srow[64];

    const int t = threadIdx.x;
    const int l = t & 63, w = t >> 6, q = l >> 4, nl = l & 15;
    const int fq = 4 * q;
    const int ge = l >> 2, part = l & 3;

    {
        const int4* s2 = (const int4*)pw2l;
        int4* d2p = (int4*)lw2;
#pragma unroll
        for (int i = 0; i < 2; ++i) d2p[t + 256 * i] = s2[t + 256 * i];
        if (t < 64) {
            w128s[t] = w1f32[128 * 64 + t];
            b2s[t] = b2v[t];
            cws[t] = cwv[t];
        }
    }
    const float cb0 = cbv[0];
    __syncthreads();

    for (int tile = blockIdx.x; tile < NTILES; tile += gridDim.x) {
        const int eo = tile * TE + w * 16;

        const int r_g = rows_s[eo + ge], c_g = cols_s[eo + ge];
        float rx = x[r_g * 3 + 0] - x[c_g * 3 + 0];
        float ry = x[r_g * 3 + 1] - x[c_g * 3 + 1];
        float rz = x[r_g * 3 + 2] - x[c_g * 3 + 2];
        float d2 = fmaf(rx, rx, fmaf(ry, ry, rz * rz));
        if (part == 0) {
            srow[w * 16 + ge] = r_g;
            float4 rv;
            rv.x = rx; rv.y = ry; rv.z = rz; rv.w = d2;
            *(float4*)&relsm[(w * 16 + ge) * 4] = rv;
        }

        const bf16* par = Pa + ((size_t)r_g << 6) + part * 16;
        const bf16* pbc = Pb + ((size_t)c_g << 6) + part * 16;
        int4 Ai = *(const int4*)(par);
        int4 Aj = *(const int4*)(par + 8);
        int4 Bi = *(const int4*)(pbc);
        int4 Bj = *(const int4*)(pbc + 8);
        const float4 w0 = *(const float4*)&w128s[part * 16 + 0];
        const float4 w1 = *(const float4*)&w128s[part * 16 + 4];
        const float4 w2q = *(const float4*)&w128s[part * 16 + 8];
        const float4 w3 = *(const float4*)&w128s[part * 16 + 12];

        int pk[8];
        pk[0] = pack2bf(silu_f(fmaf(w0.x, d2, unlo(Ai.x) + unlo(Bi.x))),
                        silu_f(fmaf(w0.y, d2, unhi(Ai.x) + unhi(Bi.x))));
        pk[1] = pack2bf(silu_f(fmaf(w0.z, d2, unlo(Ai.y) + unlo(Bi.y))),
                        silu_f(fmaf(w0.w, d2, unhi(Ai.y) + unhi(Bi.y))));
        pk[2] = pack2bf(silu_f(fmaf(w1.x, d2, unlo(Ai.z) + unlo(Bi.z))),
                        silu_f(fmaf(w1.y, d2, unhi(Ai.z) + unhi(Bi.z))));
        pk[3] = pack2bf(silu_f(fmaf(w1.z, d2, unlo(Ai.w) + unlo(Bi.w))),
                        silu_f(fmaf(w1.w, d2, unhi(Ai.w) + unhi(Bi.w))));
        pk[4] = pack2bf(silu_f(fmaf(w2q.x, d2, unlo(Aj.x) + unlo(Bj.x))),
                        silu_f(fmaf(w2q.y, d2, unhi(Aj.x) + unhi(Bj.x))));
        pk[5] = pack2bf(silu_f(fmaf(w2q.z, d2, unlo(Aj.y) + unlo(Bj.y))),
                        silu_f(fmaf(w2q.w, d2, unhi(Aj.y) + unhi(Bj.y))));
        pk[6] = pack2bf(silu_f(fmaf(w3.x, d2, unlo(Aj.z) + unlo(Bj.z))),
                        silu_f(fmaf(w3.y, d2, unhi(Aj.z) + unhi(Bj.z))));
        pk[7] = pack2bf(silu_f(fmaf(w3.z, d2, unlo(Aj.w) + unlo(Bj.w))),
                        silu_f(fmaf(w3.w, d2, unhi(Aj.w) + unhi(Bj.w))));

        f32x4 a2[4];
#pragma unroll
        for (int T = 0; T < 4; ++T) a2[T] = (f32x4){0.f, 0.f, 0.f, 0.f};
#pragma unroll
        for (int c2 = 0; c2 < 2; ++c2) {
            union { int i[4]; bf16x8 v; } bu;
            int src = nl * 4 + 2 * c2 + (q >> 1);
#pragma unroll
            for (int d = 0; d < 4; ++d) {
                int t0 = __shfl(pk[d], src);
                int t1 = __shfl(pk[4 + d], src);
                bu.i[d] = (q & 1) ? t1 : t0;
            }
#pragma unroll
            for (int T = 0; T < 4; ++T) {
                bf16x8 wf = *(const bf16x8*)&lw2[(((c2 * 4 + T) * 64) + l) << 3];
                a2[T] = __builtin_amdgcn_mfma_f32_16x16x32_bf16(wf, bu.v, a2[T], 0, 0, 0);
            }
        }
        float pc = 0.f;
#pragma unroll
        for (int T = 0; T < 4; ++T) {
            const float4 bq = *(const float4*)&b2s[T * 16 + fq];
            const float4 cq = *(const float4*)&cws[T * 16 + fq];
            float m0 = silu_f(a2[T][0] + bq.x);
            float m1 = silu_f(a2[T][1] + bq.y);
            float m2 = silu_f(a2[T][2] + bq.z);
            float m3 = silu_f(a2[T][3] + bq.w);
            int p0 = (T * 16 + fq) >> 1;
            mEp[(p0 + 0) * 65 + w * 16 + nl] = pack2bf(m0, m1);
            mEp[(p0 + 1) * 65 + w * 16 + nl] = pack2bf(m2, m3);
            pc += m0 * cq.x + m1 * cq.y + m2 * cq.z + m3 * cq.w;
        }
        pc += __shfl_xor(pc, 16);
        pc += __shfl_xor(pc, 32);
        if (q == 0) coefs[w * 16 + nl] = tanh_f(pc + cb0);
        __syncthreads();  // barrier A

        {
            int rl = srow[l];
            int rprev = __shfl(rl, l - 1);
            bool isst = (l == 0) || (rl != rprev);
            unsigned long long mask = __ballot(isst);
            const int pair = l & 31, half = l >> 5;
            unsigned long long mm = mask;
            int s = 0;
            while (mm) {
                int st = __ffsll(mm) - 1;
                mm &= mm - 1;
                if ((s & 3) == w) {
                    int en = mm ? (__ffsll(mm) - 1) : TE;
                    int row = __shfl(rl, st);
                    float s0 = 0.f, s1 = 0.f, sx = 0.f;
                    for (int e = st + half; e < en; e += 2) {
                        int pv = mEp[pair * 65 + e];
                        s0 += __builtin_bit_cast(float, pv << 16);
                        s1 += __builtin_bit_cast(float, pv & 0xffff0000);
                    }
                    if (half == 1 && pair < 3) {
                        for (int e = st; e < en; ++e)
                            sx += relsm[e * 4 + pair] * coefs[e];
                    }
                    s0 += __shfl_xor(s0, 32);
                    s1 += __shfl_xor(s1, 32);
                    if (half == 0) {
                        atomicAdd(m_agg + (size_t)row * 64 + 2 * pair, s0);
                        atomicAdd(m_agg + (size_t)row * 64 + 2 * pair + 1, s1);
                    } else if (pair < 3) {
                        atomicAdd(x_acc + (size_t)row * 3 + pair, sx);
                    }
                }
                s++;
            }
        }
        __syncthreads();  // barrier B
    }
}

// ---------------- node kernel (MFMA, grid-stride; fused next-layer projection; zeroes accumulators) ----------------
__global__ __launch_bounds__(256) void k_node(
    float* __restrict__ m_agg, float* __restrict__ x_acc,
    const bf16* __restrict__ pn1l, const bf16* __restrict__ pn2l,
    const float* __restrict__ b1v, const float* __restrict__ b2v,
    float* __restrict__ h, bf16* __restrict__ hbuf, float* __restrict__ x,
    const bf16* __restrict__ pw1n, const float* __restrict__ b1n,
    bf16* __restrict__ Pa, bf16* __restrict__ Pb, int donext) {
    __shared__ __align__(16) bf16 inB[16 * 64 * 8];
    __shared__ float dhT[64 * 65];
    __shared__ __align__(16) float sb1[64], sb2[64], sb1n[64];

    const int t = threadIdx.x;
    const int l = t & 63, w = t >> 6, q = l >> 4, nl = l & 15;
    const int qh = q >> 1, qb = 2 * (q & 1), fq = 4 * q;
    const int ge = t >> 2, part = t & 3;

    bf16x8 w1f[4][4];
#pragma unroll
    for (int kc = 0; kc < 4; ++kc)
#pragma unroll
        for (int T = 0; T < 4; ++T)
            w1f[kc][T] = *(const bf16x8*)(pn1l + (((kc * 4 + T) * 64 + l) << 3));
    bf16x8 w2f[2][4];
#pragma unroll
    for (int c = 0; c < 2; ++c)
#pragma unroll
        for (int T = 0; T < 4; ++T)
            w2f[c][T] = *(const bf16x8*)(pn2l + (((c * 4 + T) * 64 + l) << 3));
    if (t < 64) { sb1[t] = b1v[t]; sb2[t] = b2v[t]; sb1n[t] = b1n[t]; }

    const int NT = (Nn + 63) / 64;
    for (int bt = blockIdx.x; bt < NT; bt += gridDim.x) {
        const int base = bt * 64;
        const int n_g = base + ge;
        __syncthreads();
        {
            if (n_g < Nn) {
                const bf16* hr = hbuf + ((size_t)n_g << 6) + part * 16;
                *(bf16x8*)&inB[(((part * 2 + 0) * 64) + ge) << 3] = *(const bf16x8*)(hr);
                *(bf16x8*)&inB[(((part * 2 + 1) * 64) + ge) << 3] = *(const bf16x8*)(hr + 8);
                float* mr = m_agg + ((size_t)n_g << 6) + part * 16;
                float4 m0 = *(const float4*)(mr + 0);
                float4 m1 = *(const float4*)(mr + 4);
                float4 m2 = *(const float4*)(mr + 8);
                float4 m3 = *(const float4*)(mr + 12);
                float4 z4 = {0.f, 0.f, 0.f, 0.f};
                *(float4*)(mr + 0) = z4;
                *(float4*)(mr + 4) = z4;
                *(float4*)(mr + 8) = z4;
                *(float4*)(mr + 12) = z4;
                bf16x8 bm0 = {(bf16)m0.x, (bf16)m0.y, (bf16)m0.z, (bf16)m0.w,
                              (bf16)m1.x, (bf16)m1.y, (bf16)m1.z, (bf16)m1.w};
                bf16x8 bm1 = {(bf16)m2.x, (bf16)m2.y, (bf16)m2.z, (bf16)m2.w,
                              (bf16)m3.x, (bf16)m3.y, (bf16)m3.z, (bf16)m3.w};
                *(bf16x8*)&inB[(((8 + part * 2 + 0) * 64) + ge) << 3] = bm0;
                *(bf16x8*)&inB[(((8 + part * 2 + 1) * 64) + ge) << 3] = bm1;
            } else {
                bf16x8 zz = {(bf16)0.f, (bf16)0.f, (bf16)0.f, (bf16)0.f,
                             (bf16)0.f, (bf16)0.f, (bf16)0.f, (bf16)0.f};
                *(bf16x8*)&inB[(((part * 2 + 0) * 64) + ge) << 3] = zz;
                *(bf16x8*)&inB[(((part * 2 + 1) * 64) + ge) << 3] = zz;
                *(bf16x8*)&inB[(((8 + part * 2 + 0) * 64) + ge) << 3] = zz;
                *(bf16x8*)&inB[(((8 + part * 2 + 1) * 64) + ge) << 3] = zz;
            }
        }
        __syncthreads();

        f32x4 a1[4];
#pragma unroll
        for (int T = 0; T < 4; ++T) a1[T] = (f32x4){0.f, 0.f, 0.f, 0.f};
#pragma unroll
        for (int kc = 0; kc < 4; ++kc) {
            bf16x8 bfrag = *(const bf16x8*)&inB[(((kc * 4 + q) * 64) + w * 16 + nl) << 3];
#pragma unroll
            for (int T = 0; T < 4; ++T)
                a1[T] = __builtin_amdgcn_mfma_f32_16x16x32_bf16(w1f[kc][T], bfrag, a1[T], 0, 0, 0);
        }
        int pk[4][2];
#pragma unroll
        for (int T = 0; T < 4; ++T) {
            const float4 bq = *(const float4*)&sb1[T * 16 + fq];
            float h0 = silu_f(a1[T][0] + bq.x);
            float h1 = silu_f(a1[T][1] + bq.y);
            float h2 = silu_f(a1[T][2] + bq.z);
            float h3 = silu_f(a1[T][3] + bq.w);
            pk[T][0] = pack2bf(h0, h1);
            pk[T][1] = pack2bf(h2, h3);
        }
        f32x4 a2[4];
#pragma unroll
        for (int T = 0; T < 4; ++T) a2[T] = (f32x4){0.f, 0.f, 0.f, 0.f};
#pragma unroll
        for (int c = 0; c < 2; ++c) {
            union { int i[4]; bf16x8 v; } bu;
#pragma unroll
            for (int d = 0; d < 4; ++d) {
                int src = (qb + (d >> 1)) * 16 + nl;
                int t0 = __shfl(pk[2 * c][d & 1], src);
                int t1 = __shfl(pk[2 * c + 1][d & 1], src);
                bu.i[d] = qh ? t1 : t0;
            }
#pragma unroll
            for (int T = 0; T < 4; ++T)
                a2[T] = __builtin_amdgcn_mfma_f32_16x16x32_bf16(w2f[c][T], bu.v, a2[T], 0, 0, 0);
        }
#pragma unroll
        for (int T = 0; T < 4; ++T) {
            const float4 bq = *(const float4*)&sb2[T * 16 + fq];
            dhT[(T * 16 + fq + 0) * 65 + w * 16 + nl] = a2[T][0] + bq.x;
            dhT[(T * 16 + fq + 1) * 65 + w * 16 + nl] = a2[T][1] + bq.y;
            dhT[(T * 16 + fq + 2) * 65 + w * 16 + nl] = a2[T][2] + bq.z;
            dhT[(T * 16 + fq + 3) * 65 + w * 16 + nl] = a2[T][3] + bq.w;
        }
        __syncthreads();
        {
            if (n_g < Nn) {
                bf16x4 hv[4];
#pragma unroll
                for (int j = 0; j < 4; ++j) {
                    int f = part * 16 + j * 4;
                    float4* hp = (float4*)(h + ((size_t)n_g << 6) + f);
                    float4 old = *hp;
                    old.x += dhT[(f + 0) * 65 + ge];
                    old.y += dhT[(f + 1) * 65 + ge];
                    old.z += dhT[(f + 2) * 65 + ge];
                    old.w += dhT[(f + 3) * 65 + ge];
                    *hp = old;
                    hv[j] = (bf16x4){(bf16)old.x, (bf16)old.y, (bf16)old.z, (bf16)old.w};
                    *(bf16x4*)(hbuf + ((size_t)n_g << 6) + f) = hv[j];
                }
                if (donext) {
                    union { bf16x4 h2[2]; bf16x8 v; } u0, u1;
                    u0.h2[0] = hv[0]; u0.h2[1] = hv[1];
                    u1.h2[0] = hv[2]; u1.h2[1] = hv[3];
                    *(bf16x8*)&inB[(((part * 2 + 0) * 64) + ge) << 3] = u0.v;
                    *(bf16x8*)&inB[(((part * 2 + 1) * 64) + ge) << 3] = u1.v;
                }
            } else if (donext) {
                bf16x8 zz = {(bf16)0.f, (bf16)0.f, (bf16)0.f, (bf16)0.f,
                             (bf16)0.f, (bf16)0.f, (bf16)0.f, (bf16)0.f};
                *(bf16x8*)&inB[(((part * 2 + 0) * 64) + ge) << 3] = zz;
                *(bf16x8*)&inB[(((part * 2 + 1) * 64) + ge) << 3] = zz;
            }
        }
        if (t < 64) {
            int n = base + t;
            if (n < Nn) {
#pragma unroll
                for (int c = 0; c < 3; ++c) {
                    x[n * 3 + c] += x_acc[n * 3 + c];
                    x_acc[n * 3 + c] = 0.f;
                }
            }
        }
        if (!donext) continue;
        __syncthreads();
        f32x4 apa[4], apb[4];
#pragma unroll
        for (int T = 0; T < 4; ++T) {
            apa[T] = (f32x4){0.f, 0.f, 0.f, 0.f};
            apb[T] = (f32x4){0.f, 0.f, 0.f, 0.f};
        }
#pragma unroll
        for (int kc = 0; kc < 2; ++kc) {
            bf16x8 bfrag = *(const bf16x8*)&inB[(((kc * 4 + q) * 64) + w * 16 + nl) << 3];
#pragma unroll
            for (int T = 0; T < 4; ++T) {
                bf16x8 wa = *(const bf16x8*)(pw1n + (((kc * 4 + T) * 64 + l) << 3));
                bf16x8 wb = *(const bf16x8*)(pw1n + ((((kc + 2) * 4 + T) * 64 + l) << 3));
                apa[T] = __builtin_amdgcn_mfma_f32_16x16x32_bf16(wa, bfrag, apa[T], 0, 0, 0);
                apb[T] = __builtin_amdgcn_mfma_f32_16x16x32_bf16(wb, bfrag, apb[T], 0, 0, 0);
            }
        }
#pragma unroll
        for (int T = 0; T < 4; ++T) {
#pragma unroll
            for (int r = 0; r < 4; ++r)
                dhT[(T * 16 + fq + r) * 65 + w * 16 + nl] = apa[T][r] + sb1n[T * 16 + fq + r];
        }
        __syncthreads();
        if (n_g < Nn) {
#pragma unroll
            for (int j = 0; j < 4; ++j) {
                int f = part * 16 + j * 4;
                bf16x4 bv = {(bf16)dhT[(f + 0) * 65 + ge], (bf16)dhT[(f + 1) * 65 + ge],
                             (bf16)dhT[(f + 2) * 65 + ge], (bf16)dhT[(f + 3) * 65 + ge]};
                *(bf16x4*)(Pa + ((size_t)n_g << 6) + f) = bv;
            }
        }
        __syncthreads();
#pragma unroll
        for (int T = 0; T < 4; ++T) {
#pragma unroll
            for (int r = 0; r < 4; ++r)
                dhT[(T * 16 + fq + r) * 65 + w * 16 + nl] = apb[T][r];
        }
        __syncthreads();
        if (n_g < Nn) {
#pragma unroll
            for (int j = 0; j < 4; ++j) {
                int f = part * 16 + j * 4;
                bf16x4 bv = {(bf16)dhT[(f + 0) * 65 + ge], (bf16)dhT[(f + 1) * 65 + ge],
                             (bf16)dhT[(f + 2) * 65 + ge], (bf16)dhT[(f + 3) * 65 + ge]};
                *(bf16x4*)(Pb + ((size_t)n_g << 6) + f) = bv;
            }
        }
    }
}

// ---------------- readout q (MFMA) + batch stats fused ----------------
__global__ __launch_bounds__(256) void k_q(
    const bf16* __restrict__ hbuf, const bf16* __restrict__ pq1,
    const float* __restrict__ b1v, const float* __restrict__ w2v,
    const float* __restrict__ b2v, float* __restrict__ qout,
    const int* __restrict__ batch, const float* __restrict__ x,
    float* __restrict__ cnt, float* __restrict__ xs) {
    __shared__ __align__(16) bf16 inB[8 * 64 * 8];
    __shared__ __align__(16) float sb1[64], sw2[64];
    const int t = threadIdx.x;
    const int l = t & 63, w = t >> 6, q = l >> 4, nl = l & 15;
    const int fq = 4 * q;
    const int ge = t >> 2, part = t & 3;

    bf16x8 w1f[2][4];
#pragma unroll
    for (int kc = 0; kc < 2; ++kc)
#pragma unroll
        for (int T = 0; T < 4; ++T)
            w1f[kc][T] = *(const bf16x8*)(pq1 + (((kc * 4 + T) * 64 + l) << 3));
    if (t < 64) { sb1[t] = b1v[t]; sw2[t] = w2v[t]; }
    const float qb2 = b2v[0];

    const int base = blockIdx.x * 64;
    if (t < 64) {
        int n = base + t;
        if (n < Nn) {
            int b = batch[n];
            atomicAdd(&cnt[b], 1.f);
            atomicAdd(&xs[b * 3 + 0], x[n * 3 + 0]);
            atomicAdd(&xs[b * 3 + 1], x[n * 3 + 1]);
            atomicAdd(&xs[b * 3 + 2], x[n * 3 + 2]);
        }
    }
    {
        int n = base + ge;
        if (n < Nn) {
            const bf16* hr = hbuf + ((size_t)n << 6) + part * 16;
            *(bf16x8*)&inB[(((part * 2 + 0) * 64) + ge) << 3] = *(const bf16x8*)(hr);
            *(bf16x8*)&inB[(((part * 2 + 1) * 64) + ge) << 3] = *(const bf16x8*)(hr + 8);
        } else {
            bf16x8 zz = {(bf16)0.f, (bf16)0.f, (bf16)0.f, (bf16)0.f,
                         (bf16)0.f, (bf16)0.f, (bf16)0.f, (bf16)0.f};
            *(bf16x8*)&inB[(((part * 2 + 0) * 64) + ge) << 3] = zz;
            *(bf16x8*)&inB[(((part * 2 + 1) * 64) + ge) << 3] = zz;
        }
    }
    __syncthreads();
    f32x4 a1[4];
#pragma unroll
    for (int T = 0; T < 4; ++T) a1[T] = (f32x4){0.f, 0.f, 0.f, 0.f};
#pragma unroll
    for (int kc = 0; kc < 2; ++kc) {
        bf16x8 bfrag = *(const bf16x8*)&inB[(((kc * 4 + q) * 64) + w * 16 + nl) << 3];
#pragma unroll
        for (int T = 0; T < 4; ++T)
            a1[T] = __builtin_amdgcn_mfma_f32_16x16x32_bf16(w1f[kc][T], bfrag, a1[T], 0, 0, 0);
    }
    float pc = 0.f;
#pragma unroll
    for (int T = 0; T < 4; ++T) {
        const float4 bq = *(const float4*)&sb1[T * 16 + fq];
        const float4 cq = *(const float4*)&sw2[T * 16 + fq];
        pc += silu_f(a1[T][0] + bq.x) * cq.x;
        pc += silu_f(a1[T][1] + bq.y) * cq.y;
        pc += silu_f(a1[T][2] + bq.z) * cq.z;
        pc += silu_f(a1[T][3] + bq.w) * cq.w;
    }
    pc += __shfl_xor(pc, 16);
    pc += __shfl_xor(pc, 32);
    if (q == 0) {
        int n = base + w * 16 + nl;
        if (n < Nn) qout[n] = pc + qb2;
    }
}

__global__ void k_mu(const int* __restrict__ batch, const float* __restrict__ x,
                     const float* __restrict__ q, const float* __restrict__ cnt,
                     const float* __restrict__ xs, float* __restrict__ out) {
    int n = blockIdx.x * blockDim.x + threadIdx.x;
    if (n < Nn) {
        int b = batch[n];
        float cc = fmaxf(cnt[b], 1.f);
        float qn = q[n];
#pragma unroll
        for (int c = 0; c < 3; ++c) {
            float xr = x[n * 3 + c] - xs[b * 3 + c] / cc;
            atomicAdd(&out[b * 3 + c], qn * xr);
        }
    }
}

// ---------------- launch ----------------
extern "C" void kernel_launch(void* const* d_in, const int* in_sizes, int n_in,
                              void* d_out, int out_size, void* d_ws, size_t ws_size,
                              hipStream_t stream) {
    const int* z = (const int*)d_in[0];
    const float* pos = (const float*)d_in[1];
    const int* ei0 = (const int*)d_in[2];
    const int* ei1 = ei0 + Ee;
    const int* batch = (const int*)d_in[3];
    const float* emb = (const float*)d_in[4];
    const float* eW1 = (const float*)d_in[5];
    const float* eb1 = (const float*)d_in[6];
    const float* eW2 = (const float*)d_in[7];
    const float* eb2 = (const float*)d_in[8];
    const float* cW = (const float*)d_in[9];
    const float* cb = (const float*)d_in[10];
    const float* nW1 = (const float*)d_in[11];
    const float* nb1 = (const float*)d_in[12];
    const float* nW2 = (const float*)d_in[13];
    const float* nb2 = (const float*)d_in[14];
    const float* qW1 = (const float*)d_in[15];
    const float* qb1 = (const float*)d_in[16];
    const float* qW2 = (const float*)d_in[17];
    const float* qb2 = (const float*)d_in[18];

    char* ws = (char*)d_ws;
    size_t o = 0;
    auto alloc = [&](size_t bytes) {
        size_t r = o;
        o = (o + bytes + 255) & ~(size_t)255;
        return r;
    };
    float* h = (float*)(ws + alloc((size_t)Nn * 64 * 4));
    float* xp = (float*)(ws + alloc((size_t)Nn * 3 * 4));
    float* magg = (float*)(ws + alloc((size_t)Nn * 64 * 4));
    float* xacc = (float*)(ws + alloc((size_t)Nn * 3 * 4));
    size_t zero_span = (size_t)((char*)xacc - (char*)magg) + (size_t)Nn * 3 * 4;
    float* qv = (float*)(ws + alloc((size_t)Nn * 4));
    int* deg = (int*)(ws + alloc((size_t)Nn * 4));
    int* cur = (int*)(ws + alloc((size_t)Nn * 4));
    int* rows_s = (int*)(ws + alloc((size_t)Ee * 4));
    int* cols_s = (int*)(ws + alloc((size_t)Ee * 4));
    float* cnt = (float*)(ws + alloc((size_t)Bb * 4));
    float* xs = (float*)(ws + alloc((size_t)Bb * 3 * 4));
    bf16* hbm = (bf16*)(ws + alloc((size_t)Nn * 64 * 2));
    bf16* Pa = (bf16*)(ws + alloc((size_t)Nn * 64 * 2));
    bf16* Pb = (bf16*)(ws + alloc((size_t)Nn * 64 * 2));
    bf16* pw1 = (bf16*)(ws + alloc((size_t)4 * 8192 * 2));
    bf16* pw2 = (bf16*)(ws + alloc((size_t)4 * 4096 * 2));
    bf16* pn1 = (bf16*)(ws + alloc((size_t)4 * 8192 * 2));
    bf16* pn2 = (bf16*)(ws + alloc((size_t)4 * 4096 * 2));
    bf16* pq1 = (bf16*)(ws + alloc((size_t)4096 * 2));
    int* bsum = (int*)(ws + alloc((size_t)NB * 4));
    int* boff = (int*)(ws + alloc((size_t)NB * 4));

    hipMemsetAsync(deg, 0, (size_t)Nn * 4, stream);
    hipMemsetAsync(magg, 0, zero_span, stream);
    hipMemsetAsync(cnt, 0, (size_t)Bb * 4, stream);
    hipMemsetAsync(xs, 0, (size_t)Bb * 3 * 4, stream);
    hipMemsetAsync(d_out, 0, (size_t)out_size * 4, stream);

    k_init_h<<<(Nn * 64 + 255) / 256, 256, 0, stream>>>(h, hbm, z, emb);
    hipMemcpyAsync(xp, pos, (size_t)Nn * 3 * 4, hipMemcpyDeviceToDevice, stream);
    k_pack<<<(102400 + 255) / 256, 256, 0, stream>>>(eW1, eW2, nW1, nW2, qW1,
                                                     pw1, pw2, pn1, pn2, pq1);
    k_hist<<<(Ee + 255) / 256, 256, 0, stream>>>(ei0, deg);
    k_scan1<<<NB, 256, 0, stream>>>(deg, bsum);
    k_scan2<<<1, 256, 0, stream>>>(bsum, boff);
    k_scan3<<<NB, 256, 0, stream>>>(deg, boff, cur, rows_s);
    k_scatter<<<(Ee + 255) / 256, 256, 0, stream>>>(ei0, ei1, cur, cols_s);

    k_proj<<<782, 256, 0, stream>>>(hbm, pw1, eb1, Pa, Pb);
    for (int l = 0; l < 4; ++l) {
        k_edge<<<2048, 256, 0, stream>>>(rows_s, cols_s, Pa, Pb, xp,
                                         pw2 + (size_t)l * 4096,
                                         eW1 + (size_t)l * 129 * 64,
                                         eb2 + l * 64,
                                         cW + l * 64, cb + l, magg, xacc);
        int nx = (l < 3) ? (l + 1) : 0;
        k_node<<<768, 256, 0, stream>>>(magg, xacc,
                                        pn1 + (size_t)l * 8192, pn2 + (size_t)l * 4096,
                                        nb1 + l * 64, nb2 + l * 64,
                                        h, hbm, xp,
                                        pw1 + (size_t)nx * 8192, eb1 + nx * 64,
                                        Pa, Pb, (l < 3) ? 1 : 0);
    }
    k_q<<<(Nn + 63) / 64, 256, 0, stream>>>(hbm, pq1, qb1, qW2, qb2, qv,
                                            batch, xp, cnt, xs);
    k_mu<<<(Nn + 255) / 256, 256, 0, stream>>>(batch, xp, qv, cnt, xs, (float*)d_out);
}

// Round 20
// 986.354 us; speedup vs baseline: 1.0699x; 1.0195x over previous
//
#include <hip/hip_runtime.h>
#include <math.h>

#define Nn 50000
#define Ee 1600000
#define Bb 512
#define TE 64
#define NTILES (Ee / TE)
#define NB ((Nn + 255) / 256)

typedef __bf16 bf16;
typedef __bf16 bf16x8 __attribute__((ext_vector_type(8)));
typedef __bf16 bf16x4 __attribute__((ext_vector_type(4)));
typedef float f32x4 __attribute__((ext_vector_type(4)));

__device__ __forceinline__ float silu_f(float v) {
    return v * __builtin_amdgcn_rcpf(1.f + __expf(-v));
}
__device__ __forceinline__ float tanh_f(float x) {
    float e = __expf(2.f * x);
    return 1.f - 2.f * __builtin_amdgcn_rcpf(e + 1.f);
}
__device__ __forceinline__ int pack2bf(float a, float b) {
    unsigned short ua = __builtin_bit_cast(unsigned short, (bf16)a);
    unsigned short ub = __builtin_bit_cast(unsigned short, (bf16)b);
    return (int)ua | ((int)ub << 16);
}
__device__ __forceinline__ float unlo(int v) {
    return __builtin_bit_cast(float, v << 16);
}
__device__ __forceinline__ float unhi(int v) {
    return __builtin_bit_cast(float, v & 0xffff0000);
}

// ---------------- weight packing into MFMA A-fragment order ----------------
__device__ __forceinline__ void packfrag(bf16* dst, const float* src, int idx) {
    int j = idx & 7, lane = (idx >> 3) & 63, gT = idx >> 9;
    int kc = gT >> 2, T = gT & 3;
    int k = kc * 32 + (lane >> 4) * 8 + j;
    int n = T * 16 + (lane & 15);
    dst[idx] = (bf16)src[k * 64 + n];
}

// fused setup: h=emb[z] (fp32+bf16), weight packing, degree histogram (independent jobs)
#define SETUP_TOT (Nn * 64 + 102400 + Ee)
__global__ void k_setup(float* __restrict__ h, bf16* __restrict__ hb,
                        const int* __restrict__ z, const float* __restrict__ emb,
                        const float* __restrict__ eW1, const float* __restrict__ eW2,
                        const float* __restrict__ nW1, const float* __restrict__ nW2,
                        const float* __restrict__ qW1,
                        bf16* __restrict__ pw1, bf16* __restrict__ pw2,
                        bf16* __restrict__ pn1, bf16* __restrict__ pn2,
                        bf16* __restrict__ pq1,
                        const int* __restrict__ rows, int* __restrict__ deg) {
    for (int i = blockIdx.x * blockDim.x + threadIdx.x; i < SETUP_TOT;
         i += gridDim.x * blockDim.x) {
        if (i < Nn * 64) {
            int n = i >> 6, f = i & 63;
            float v = emb[z[n] * 64 + f];
            h[i] = v;
            hb[i] = (bf16)v;
        } else if (i < Nn * 64 + 102400) {
            int tid = i - Nn * 64;
            if (tid < 32768) {
                int l = tid >> 13, idx = tid & 8191;
                packfrag(pw1 + l * 8192, eW1 + (size_t)l * 129 * 64, idx);
            } else if (tid < 49152) {
                int k = tid - 32768, l = k >> 12, idx = k & 4095;
                packfrag(pw2 + l * 4096, eW2 + (size_t)l * 4096, idx);
            } else if (tid < 81920) {
                int k = tid - 49152, l = k >> 13, idx = k & 8191;
                packfrag(pn1 + l * 8192, nW1 + (size_t)l * 8192, idx);
            } else if (tid < 98304) {
                int k = tid - 81920, l = k >> 12, idx = k & 4095;
                packfrag(pn2 + l * 4096, nW2 + (size_t)l * 4096, idx);
            } else {
                packfrag(pq1, qW1, tid - 98304);
            }
        } else {
            int e = i - Nn * 64 - 102400;
            atomicAdd(&deg[rows[e]], 1);
        }
    }
}

__global__ void k_scan1(const int* __restrict__ deg, int* __restrict__ bsum) {
    __shared__ int red[4];
    int b = blockIdx.x;
    int i = b * 256 + threadIdx.x;
    int v = (i < Nn) ? deg[i] : 0;
#pragma unroll
    for (int off = 1; off < 64; off <<= 1) v += __shfl_xor(v, off);
    if ((threadIdx.x & 63) == 0) red[threadIdx.x >> 6] = v;
    __syncthreads();
    if (threadIdx.x == 0) bsum[b] = red[0] + red[1] + red[2] + red[3];
}

__global__ void k_scan2(const int* __restrict__ bsum, int* __restrict__ boff) {
    __shared__ int s[256];
    int t = threadIdx.x;
    int v = (t < NB) ? bsum[t] : 0;
    s[t] = v;
    __syncthreads();
    for (int off = 1; off < 256; off <<= 1) {
        int u = (t >= off) ? s[t - off] : 0;
        __syncthreads();
        s[t] += u;
        __syncthreads();
    }
    if (t < NB) boff[t] = s[t] - v;
}

// fused: exclusive scan -> cur (scatter cursor) + rows_s expansion
__global__ void k_scan3(const int* __restrict__ deg, const int* __restrict__ boff,
                        int* __restrict__ cur, int* __restrict__ rows_s) {
    __shared__ int s[256];
    int b = blockIdx.x, t = threadIdx.x;
    int i = b * 256 + t;
    int v = (i < Nn) ? deg[i] : 0;
    s[t] = v;
    __syncthreads();
    for (int off = 1; off < 256; off <<= 1) {
        int u = (t >= off) ? s[t - off] : 0;
        __syncthreads();
        s[t] += u;
        __syncthreads();
    }
    if (i < Nn) {
        int en = boff[b] + s[t];
        int st = en - v;
        cur[i] = st;
        for (int o = st; o < en; ++o) rows_s[o] = i;
    }
}

// cols-only scatter; cur holds absolute offsets
__global__ void k_scatter(const int* __restrict__ rows, const int* __restrict__ cols,
                          int* __restrict__ cur, int* __restrict__ cols_s) {
    int e = blockIdx.x * blockDim.x + threadIdx.x;
    if (e < Ee) {
        int o = atomicAdd(&cur[rows[e]], 1);
        cols_s[o] = cols[e];
    }
}

// ---------------- layer-0 node projection: Pa = H@W1a + b1, Pb = H@W1b (bf16 out) ----------------
__global__ __launch_bounds__(256) void k_proj(
    const bf16* __restrict__ hbuf, const bf16* __restrict__ pw1l,
    const float* __restrict__ b1v,
    bf16* __restrict__ Pa, bf16* __restrict__ Pb) {
    __shared__ __align__(16) bf16 inB[8 * 64 * 8];
    __shared__ float dhT[64 * 65];
    __shared__ __align__(16) float sb1[64];

    const int t = threadIdx.x;
    const int l = t & 63, w = t >> 6, q = l >> 4, nl = l & 15;
    const int fq = 4 * q;
    const int ge = t >> 2, part = t & 3;

    bf16x8 w1f[4][4];
#pragma unroll
    for (int kc = 0; kc < 4; ++kc)
#pragma unroll
        for (int T = 0; T < 4; ++T)
            w1f[kc][T] = *(const bf16x8*)(pw1l + (((kc * 4 + T) * 64 + l) << 3));
    if (t < 64) sb1[t] = b1v[t];

    const int NT = (Nn + 63) / 64;
    for (int bt = blockIdx.x; bt < NT; bt += gridDim.x) {
        const int base = bt * 64;
        __syncthreads();
        {
            int n = base + ge;
            if (n < Nn) {
                const bf16* hr = hbuf + ((size_t)n << 6) + part * 16;
                *(bf16x8*)&inB[(((part * 2 + 0) * 64) + ge) << 3] = *(const bf16x8*)(hr);
                *(bf16x8*)&inB[(((part * 2 + 1) * 64) + ge) << 3] = *(const bf16x8*)(hr + 8);
            } else {
                bf16x8 zz = {(bf16)0.f, (bf16)0.f, (bf16)0.f, (bf16)0.f,
                             (bf16)0.f, (bf16)0.f, (bf16)0.f, (bf16)0.f};
                *(bf16x8*)&inB[(((part * 2 + 0) * 64) + ge) << 3] = zz;
                *(bf16x8*)&inB[(((part * 2 + 1) * 64) + ge) << 3] = zz;
            }
        }
        __syncthreads();

        f32x4 apa[4], apb[4];
#pragma unroll
        for (int T = 0; T < 4; ++T) {
            apa[T] = (f32x4){0.f, 0.f, 0.f, 0.f};
            apb[T] = (f32x4){0.f, 0.f, 0.f, 0.f};
        }
#pragma unroll
        for (int kc = 0; kc < 2; ++kc) {
            bf16x8 bfrag = *(const bf16x8*)&inB[(((kc * 4 + q) * 64) + w * 16 + nl) << 3];
#pragma unroll
            for (int T = 0; T < 4; ++T) {
                apa[T] = __builtin_amdgcn_mfma_f32_16x16x32_bf16(w1f[kc][T], bfrag, apa[T], 0, 0, 0);
                apb[T] = __builtin_amdgcn_mfma_f32_16x16x32_bf16(w1f[kc + 2][T], bfrag, apb[T], 0, 0, 0);
            }
        }
#pragma unroll
        for (int T = 0; T < 4; ++T) {
#pragma unroll
            for (int r = 0; r < 4; ++r)
                dhT[(T * 16 + fq + r) * 65 + w * 16 + nl] = apa[T][r] + sb1[T * 16 + fq + r];
        }
        __syncthreads();
        {
            int n = base + ge;
            if (n < Nn) {
#pragma unroll
                for (int j = 0; j < 4; ++j) {
                    int f = part * 16 + j * 4;
                    bf16x4 bv = {(bf16)dhT[(f + 0) * 65 + ge], (bf16)dhT[(f + 1) * 65 + ge],
                                 (bf16)dhT[(f + 2) * 65 + ge], (bf16)dhT[(f + 3) * 65 + ge]};
                    *(bf16x4*)(Pa + ((size_t)n << 6) + f) = bv;
                }
            }
        }
        __syncthreads();
#pragma unroll
        for (int T = 0; T < 4; ++T) {
#pragma unroll
            for (int r = 0; r < 4; ++r)
                dhT[(T * 16 + fq + r) * 65 + w * 16 + nl] = apb[T][r];
        }
        __syncthreads();
        {
            int n = base + ge;
            if (n < Nn) {
#pragma unroll
                for (int j = 0; j < 4; ++j) {
                    int f = part * 16 + j * 4;
                    bf16x4 bv = {(bf16)dhT[(f + 0) * 65 + ge], (bf16)dhT[(f + 1) * 65 + ge],
                                 (bf16)dhT[(f + 2) * 65 + ge], (bf16)dhT[(f + 3) * 65 + ge]};
                    *(bf16x4*)(Pb + ((size_t)n << 6) + f) = bv;
                }
            }
        }
    }
}

// ---------------- edge kernel: gather bf16 Pa/Pb + rank-1 + silu -> GEMM2 only ----------------
__global__ __launch_bounds__(256, 8) void k_edge(
    const int* __restrict__ rows_s, const int* __restrict__ cols_s,
    const bf16* __restrict__ Pa, const bf16* __restrict__ Pb,
    const float* __restrict__ x,
    const bf16* __restrict__ pw2l,
    const float* __restrict__ w1f32,
    const float* __restrict__ b2v,
    const float* __restrict__ cwv, const float* __restrict__ cbv,
    float* __restrict__ m_agg, float* __restrict__ x_acc) {
    __shared__ __align__(16) bf16 lw2[4096];
    __shared__ __align__(16) float w128s[64], b2s[64], cws[64];
    __shared__ int mEp[32 * 65];
    __shared__ __align__(16) float relsm[64 * 4];
    __shared__ float coefs[64];
    __shared__ int srow[64];

    const int t = threadIdx.x;
    const int l = t & 63, w = t >> 6, q = l >> 4, nl = l & 15;
    const int fq = 4 * q;
    const int ge = l >> 2, part = l & 3;

    {
        const int4* s2 = (const int4*)pw2l;
        int4* d2p = (int4*)lw2;
#pragma unroll
        for (int i = 0; i < 2; ++i) d2p[t + 256 * i] = s2[t + 256 * i];
        if (t < 64) {
            w128s[t] = w1f32[128 * 64 + t];
            b2s[t] = b2v[t];
            cws[t] = cwv[t];
        }
    }
    const float cb0 = cbv[0];
    __syncthreads();

    for (int tile = blockIdx.x; tile < NTILES; tile += gridDim.x) {
        const int eo = tile * TE + w * 16;

        const int r_g = rows_s[eo + ge], c_g = cols_s[eo + ge];
        float rx = x[r_g * 3 + 0] - x[c_g * 3 + 0];
        float ry = x[r_g * 3 + 1] - x[c_g * 3 + 1];
        float rz = x[r_g * 3 + 2] - x[c_g * 3 + 2];
        float d2 = fmaf(rx, rx, fmaf(ry, ry, rz * rz));
        if (part == 0) {
            srow[w * 16 + ge] = r_g;
            float4 rv;
            rv.x = rx; rv.y = ry; rv.z = rz; rv.w = d2;
            *(float4*)&relsm[(w * 16 + ge) * 4] = rv;
        }

        const bf16* par = Pa + ((size_t)r_g << 6) + part * 16;
        const bf16* pbc = Pb + ((size_t)c_g << 6) + part * 16;
        int4 Ai = *(const int4*)(par);
        int4 Aj = *(const int4*)(par + 8);
        int4 Bi = *(const int4*)(pbc);
        int4 Bj = *(const int4*)(pbc + 8);
        const float4 w0 = *(const float4*)&w128s[part * 16 + 0];
        const float4 w1 = *(const float4*)&w128s[part * 16 + 4];
        const float4 w2q = *(const float4*)&w128s[part * 16 + 8];
        const float4 w3 = *(const float4*)&w128s[part * 16 + 12];

        int pk[8];
        pk[0] = pack2bf(silu_f(fmaf(w0.x, d2, unlo(Ai.x) + unlo(Bi.x))),
                        silu_f(fmaf(w0.y, d2, unhi(Ai.x) + unhi(Bi.x))));
        pk[1] = pack2bf(silu_f(fmaf(w0.z, d2, unlo(Ai.y) + unlo(Bi.y))),
                        silu_f(fmaf(w0.w, d2, unhi(Ai.y) + unhi(Bi.y))));
        pk[2] = pack2bf(silu_f(fmaf(w1.x, d2, unlo(Ai.z) + unlo(Bi.z))),
                        silu_f(fmaf(w1.y, d2, unhi(Ai.z) + unhi(Bi.z))));
        pk[3] = pack2bf(silu_f(fmaf(w1.z, d2, unlo(Ai.w) + unlo(Bi.w))),
                        silu_f(fmaf(w1.w, d2, unhi(Ai.w) + unhi(Bi.w))));
        pk[4] = pack2bf(silu_f(fmaf(w2q.x, d2, unlo(Aj.x) + unlo(Bj.x))),
                        silu_f(fmaf(w2q.y, d2, unhi(Aj.x) + unhi(Bj.x))));
        pk[5] = pack2bf(silu_f(fmaf(w2q.z, d2, unlo(Aj.y) + unlo(Bj.y))),
                        silu_f(fmaf(w2q.w, d2, unhi(Aj.y) + unhi(Bj.y))));
        pk[6] = pack2bf(silu_f(fmaf(w3.x, d2, unlo(Aj.z) + unlo(Bj.z))),
                        silu_f(fmaf(w3.y, d2, unhi(Aj.z) + unhi(Bj.z))));
        pk[7] = pack2bf(silu_f(fmaf(w3.z, d2, unlo(Aj.w) + unlo(Bj.w))),
                        silu_f(fmaf(w3.w, d2, unhi(Aj.w) + unhi(Bj.w))));

        f32x4 a2[4];
#pragma unroll
        for (int T = 0; T < 4; ++T) a2[T] = (f32x4){0.f, 0.f, 0.f, 0.f};
#pragma unroll
        for (int c2 = 0; c2 < 2; ++c2) {
            union { int i[4]; bf16x8 v; } bu;
            int src = nl * 4 + 2 * c2 + (q >> 1);
#pragma unroll
            for (int d = 0; d < 4; ++d) {
                int t0 = __shfl(pk[d], src);
                int t1 = __shfl(pk[4 + d], src);
                bu.i[d] = (q & 1) ? t1 : t0;
            }
#pragma unroll
            for (int T = 0; T < 4; ++T) {
                bf16x8 wf = *(const bf16x8*)&lw2[(((c2 * 4 + T) * 64) + l) << 3];
                a2[T] = __builtin_amdgcn_mfma_f32_16x16x32_bf16(wf, bu.v, a2[T], 0, 0, 0);
            }
        }
        float pc = 0.f;
#pragma unroll
        for (int T = 0; T < 4; ++T) {
            const float4 bq = *(const float4*)&b2s[T * 16 + fq];
            const float4 cq = *(const float4*)&cws[T * 16 + fq];
            float m0 = silu_f(a2[T][0] + bq.x);
            float m1 = silu_f(a2[T][1] + bq.y);
            float m2 = silu_f(a2[T][2] + bq.z);
            float m3 = silu_f(a2[T][3] + bq.w);
            int p0 = (T * 16 + fq) >> 1;
            mEp[(p0 + 0) * 65 + w * 16 + nl] = pack2bf(m0, m1);
            mEp[(p0 + 1) * 65 + w * 16 + nl] = pack2bf(m2, m3);
            pc += m0 * cq.x + m1 * cq.y + m2 * cq.z + m3 * cq.w;
        }
        pc += __shfl_xor(pc, 16);
        pc += __shfl_xor(pc, 32);
        if (q == 0) coefs[w * 16 + nl] = tanh_f(pc + cb0);
        __syncthreads();  // barrier A

        {
            int rl = srow[l];
            int rprev = __shfl(rl, l - 1);
            bool isst = (l == 0) || (rl != rprev);
            unsigned long long mask = __ballot(isst);
            const int pair = l & 31, half = l >> 5;
            unsigned long long mm = mask;
            int s = 0;
            while (mm) {
                int st = __ffsll(mm) - 1;
                mm &= mm - 1;
                if ((s & 3) == w) {
                    int en = mm ? (__ffsll(mm) - 1) : TE;
                    int row = __shfl(rl, st);
                    float s0 = 0.f, s1 = 0.f, sx = 0.f;
                    for (int e = st + half; e < en; e += 2) {
                        int pv = mEp[pair * 65 + e];
                        s0 += __builtin_bit_cast(float, pv << 16);
                        s1 += __builtin_bit_cast(float, pv & 0xffff0000);
                    }
                    if (half == 1 && pair < 3) {
                        for (int e = st; e < en; ++e)
                            sx += relsm[e * 4 + pair] * coefs[e];
                    }
                    s0 += __shfl_xor(s0, 32);
                    s1 += __shfl_xor(s1, 32);
                    if (half == 0) {
                        atomicAdd(m_agg + (size_t)row * 64 + 2 * pair, s0);
                        atomicAdd(m_agg + (size_t)row * 64 + 2 * pair + 1, s1);
                    } else if (pair < 3) {
                        atomicAdd(x_acc + (size_t)row * 3 + pair, sx);
                    }
                }
                s++;
            }
        }
        __syncthreads();  // barrier B
    }
}

// ---------------- node kernel (MFMA, grid-stride; fused next-layer projection; zeroes accumulators) ----------------
__global__ __launch_bounds__(256) void k_node(
    float* __restrict__ m_agg, float* __restrict__ x_acc,
    const bf16* __restrict__ pn1l, const bf16* __restrict__ pn2l,
    const float* __restrict__ b1v, const float* __restrict__ b2v,
    float* __restrict__ h, bf16* __restrict__ hbuf, float* __restrict__ x,
    const bf16* __restrict__ pw1n, const float* __restrict__ b1n,
    bf16* __restrict__ Pa, bf16* __restrict__ Pb, int donext) {
    __shared__ __align__(16) bf16 inB[16 * 64 * 8];
    __shared__ float dhT[64 * 65];
    __shared__ __align__(16) float sb1[64], sb2[64], sb1n[64];

    const int t = threadIdx.x;
    const int l = t & 63, w = t >> 6, q = l >> 4, nl = l & 15;
    const int qh = q >> 1, qb = 2 * (q & 1), fq = 4 * q;
    const int ge = t >> 2, part = t & 3;

    bf16x8 w1f[4][4];
#pragma unroll
    for (int kc = 0; kc < 4; ++kc)
#pragma unroll
        for (int T = 0; T < 4; ++T)
            w1f[kc][T] = *(const bf16x8*)(pn1l + (((kc * 4 + T) * 64 + l) << 3));
    bf16x8 w2f[2][4];
#pragma unroll
    for (int c = 0; c < 2; ++c)
#pragma unroll
        for (int T = 0; T < 4; ++T)
            w2f[c][T] = *(const bf16x8*)(pn2l + (((c * 4 + T) * 64 + l) << 3));
    if (t < 64) { sb1[t] = b1v[t]; sb2[t] = b2v[t]; sb1n[t] = b1n[t]; }

    const int NT = (Nn + 63) / 64;
    for (int bt = blockIdx.x; bt < NT; bt += gridDim.x) {
        const int base = bt * 64;
        const int n_g = base + ge;
        __syncthreads();
        {
            if (n_g < Nn) {
                const bf16* hr = hbuf + ((size_t)n_g << 6) + part * 16;
                *(bf16x8*)&inB[(((part * 2 + 0) * 64) + ge) << 3] = *(const bf16x8*)(hr);
                *(bf16x8*)&inB[(((part * 2 + 1) * 64) + ge) << 3] = *(const bf16x8*)(hr + 8);
                float* mr = m_agg + ((size_t)n_g << 6) + part * 16;
                float4 m0 = *(const float4*)(mr + 0);
                float4 m1 = *(const float4*)(mr + 4);
                float4 m2 = *(const float4*)(mr + 8);
                float4 m3 = *(const float4*)(mr + 12);
                float4 z4 = {0.f, 0.f, 0.f, 0.f};
                *(float4*)(mr + 0) = z4;
                *(float4*)(mr + 4) = z4;
                *(float4*)(mr + 8) = z4;
                *(float4*)(mr + 12) = z4;
                bf16x8 bm0 = {(bf16)m0.x, (bf16)m0.y, (bf16)m0.z, (bf16)m0.w,
                              (bf16)m1.x, (bf16)m1.y, (bf16)m1.z, (bf16)m1.w};
                bf16x8 bm1 = {(bf16)m2.x, (bf16)m2.y, (bf16)m2.z, (bf16)m2.w,
                              (bf16)m3.x, (bf16)m3.y, (bf16)m3.z, (bf16)m3.w};
                *(bf16x8*)&inB[(((8 + part * 2 + 0) * 64) + ge) << 3] = bm0;
                *(bf16x8*)&inB[(((8 + part * 2 + 1) * 64) + ge) << 3] = bm1;
            } else {
                bf16x8 zz = {(bf16)0.f, (bf16)0.f, (bf16)0.f, (bf16)0.f,
                             (bf16)0.f, (bf16)0.f, (bf16)0.f, (bf16)0.f};
                *(bf16x8*)&inB[(((part * 2 + 0) * 64) + ge) << 3] = zz;
                *(bf16x8*)&inB[(((part * 2 + 1) * 64) + ge) << 3] = zz;
                *(bf16x8*)&inB[(((8 + part * 2 + 0) * 64) + ge) << 3] = zz;
                *(bf16x8*)&inB[(((8 + part * 2 + 1) * 64) + ge) << 3] = zz;
            }
        }
        __syncthreads();

        f32x4 a1[4];
#pragma unroll
        for (int T = 0; T < 4; ++T) a1[T] = (f32x4){0.f, 0.f, 0.f, 0.f};
#pragma unroll
        for (int kc = 0; kc < 4; ++kc) {
            bf16x8 bfrag = *(const bf16x8*)&inB[(((kc * 4 + q) * 64) + w * 16 + nl) << 3];
#pragma unroll
            for (int T = 0; T < 4; ++T)
                a1[T] = __builtin_amdgcn_mfma_f32_16x16x32_bf16(w1f[kc][T], bfrag, a1[T], 0, 0, 0);
        }
        int pk[4][2];
#pragma unroll
        for (int T = 0; T < 4; ++T) {
            const float4 bq = *(const float4*)&sb1[T * 16 + fq];
            float h0 = silu_f(a1[T][0] + bq.x);
            float h1 = silu_f(a1[T][1] + bq.y);
            float h2 = silu_f(a1[T][2] + bq.z);
            float h3 = silu_f(a1[T][3] + bq.w);
            pk[T][0] = pack2bf(h0, h1);
            pk[T][1] = pack2bf(h2, h3);
        }
        f32x4 a2[4];
#pragma unroll
        for (int T = 0; T < 4; ++T) a2[T] = (f32x4){0.f, 0.f, 0.f, 0.f};
#pragma unroll
        for (int c = 0; c < 2; ++c) {
            union { int i[4]; bf16x8 v; } bu;
#pragma unroll
            for (int d = 0; d < 4; ++d) {
                int src = (qb + (d >> 1)) * 16 + nl;
                int t0 = __shfl(pk[2 * c][d & 1], src);
                int t1 = __shfl(pk[2 * c + 1][d & 1], src);
                bu.i[d] = qh ? t1 : t0;
            }
#pragma unroll
            for (int T = 0; T < 4; ++T)
                a2[T] = __builtin_amdgcn_mfma_f32_16x16x32_bf16(w2f[c][T], bu.v, a2[T], 0, 0, 0);
        }
#pragma unroll
        for (int T = 0; T < 4; ++T) {
            const float4 bq = *(const float4*)&sb2[T * 16 + fq];
            dhT[(T * 16 + fq + 0) * 65 + w * 16 + nl] = a2[T][0] + bq.x;
            dhT[(T * 16 + fq + 1) * 65 + w * 16 + nl] = a2[T][1] + bq.y;
            dhT[(T * 16 + fq + 2) * 65 + w * 16 + nl] = a2[T][2] + bq.z;
            dhT[(T * 16 + fq + 3) * 65 + w * 16 + nl] = a2[T][3] + bq.w;
        }
        __syncthreads();
        {
            if (n_g < Nn) {
                bf16x4 hv[4];
#pragma unroll
                for (int j = 0; j < 4; ++j) {
                    int f = part * 16 + j * 4;
                    float4* hp = (float4*)(h + ((size_t)n_g << 6) + f);
                    float4 old = *hp;
                    old.x += dhT[(f + 0) * 65 + ge];
                    old.y += dhT[(f + 1) * 65 + ge];
                    old.z += dhT[(f + 2) * 65 + ge];
                    old.w += dhT[(f + 3) * 65 + ge];
                    *hp = old;
                    hv[j] = (bf16x4){(bf16)old.x, (bf16)old.y, (bf16)old.z, (bf16)old.w};
                    *(bf16x4*)(hbuf + ((size_t)n_g << 6) + f) = hv[j];
                }
                if (donext) {
                    union { bf16x4 h2[2]; bf16x8 v; } u0, u1;
                    u0.h2[0] = hv[0]; u0.h2[1] = hv[1];
                    u1.h2[0] = hv[2]; u1.h2[1] = hv[3];
                    *(bf16x8*)&inB[(((part * 2 + 0) * 64) + ge) << 3] = u0.v;
                    *(bf16x8*)&inB[(((part * 2 + 1) * 64) + ge) << 3] = u1.v;
                }
            } else if (donext) {
                bf16x8 zz = {(bf16)0.f, (bf16)0.f, (bf16)0.f, (bf16)0.f,
                             (bf16)0.f, (bf16)0.f, (bf16)0.f, (bf16)0.f};
                *(bf16x8*)&inB[(((part * 2 + 0) * 64) + ge) << 3] = zz;
                *(bf16x8*)&inB[(((part * 2 + 1) * 64) + ge) << 3] = zz;
            }
        }
        if (t < 64) {
            int n = base + t;
            if (n < Nn) {
#pragma unroll
                for (int c = 0; c < 3; ++c) {
                    x[n * 3 + c] += x_acc[n * 3 + c];
                    x_acc[n * 3 + c] = 0.f;
                }
            }
        }
        if (!donext) continue;
        __syncthreads();
        f32x4 apa[4], apb[4];
#pragma unroll
        for (int T = 0; T < 4; ++T) {
            apa[T] = (f32x4){0.f, 0.f, 0.f, 0.f};
            apb[T] = (f32x4){0.f, 0.f, 0.f, 0.f};
        }
#pragma unroll
        for (int kc = 0; kc < 2; ++kc) {
            bf16x8 bfrag = *(const bf16x8*)&inB[(((kc * 4 + q) * 64) + w * 16 + nl) << 3];
#pragma unroll
            for (int T = 0; T < 4; ++T) {
                bf16x8 wa = *(const bf16x8*)(pw1n + (((kc * 4 + T) * 64 + l) << 3));
                bf16x8 wb = *(const bf16x8*)(pw1n + ((((kc + 2) * 4 + T) * 64 + l) << 3));
                apa[T] = __builtin_amdgcn_mfma_f32_16x16x32_bf16(wa, bfrag, apa[T], 0, 0, 0);
                apb[T] = __builtin_amdgcn_mfma_f32_16x16x32_bf16(wb, bfrag, apb[T], 0, 0, 0);
            }
        }
#pragma unroll
        for (int T = 0; T < 4; ++T) {
#pragma unroll
            for (int r = 0; r < 4; ++r)
                dhT[(T * 16 + fq + r) * 65 + w * 16 + nl] = apa[T][r] + sb1n[T * 16 + fq + r];
        }
        __syncthreads();
        if (n_g < Nn) {
#pragma unroll
            for (int j = 0; j < 4; ++j) {
                int f = part * 16 + j * 4;
                bf16x4 bv = {(bf16)dhT[(f + 0) * 65 + ge], (bf16)dhT[(f + 1) * 65 + ge],
                             (bf16)dhT[(f + 2) * 65 + ge], (bf16)dhT[(f + 3) * 65 + ge]};
                *(bf16x4*)(Pa + ((size_t)n_g << 6) + f) = bv;
            }
        }
        __syncthreads();
#pragma unroll
        for (int T = 0; T < 4; ++T) {
#pragma unroll
            for (int r = 0; r < 4; ++r)
                dhT[(T * 16 + fq + r) * 65 + w * 16 + nl] = apb[T][r];
        }
        __syncthreads();
        if (n_g < Nn) {
#pragma unroll
            for (int j = 0; j < 4; ++j) {
                int f = part * 16 + j * 4;
                bf16x4 bv = {(bf16)dhT[(f + 0) * 65 + ge], (bf16)dhT[(f + 1) * 65 + ge],
                             (bf16)dhT[(f + 2) * 65 + ge], (bf16)dhT[(f + 3) * 65 + ge]};
                *(bf16x4*)(Pb + ((size_t)n_g << 6) + f) = bv;
            }
        }
    }
}

// ---------------- readout q (MFMA) + batch stats fused ----------------
__global__ __launch_bounds__(256) void k_q(
    const bf16* __restrict__ hbuf, const bf16* __restrict__ pq1,
    const float* __restrict__ b1v, const float* __restrict__ w2v,
    const float* __restrict__ b2v, float* __restrict__ qout,
    const int* __restrict__ batch, const float* __restrict__ x,
    float* __restrict__ cnt, float* __restrict__ xs) {
    __shared__ __align__(16) bf16 inB[8 * 64 * 8];
    __shared__ __align__(16) float sb1[64], sw2[64];
    const int t = threadIdx.x;
    const int l = t & 63, w = t >> 6, q = l >> 4, nl = l & 15;
    const int fq = 4 * q;
    const int ge = t >> 2, part = t & 3;

    bf16x8 w1f[2][4];
#pragma unroll
    for (int kc = 0; kc < 2; ++kc)
#pragma unroll
        for (int T = 0; T < 4; ++T)
            w1f[kc][T] = *(const bf16x8*)(pq1 + (((kc * 4 + T) * 64 + l) << 3));
    if (t < 64) { sb1[t] = b1v[t]; sw2[t] = w2v[t]; }
    const float qb2 = b2v[0];

    const int base = blockIdx.x * 64;
    if (t < 64) {
        int n = base + t;
        if (n < Nn) {
            int b = batch[n];
            atomicAdd(&cnt[b], 1.f);
            atomicAdd(&xs[b * 3 + 0], x[n * 3 + 0]);
            atomicAdd(&xs[b * 3 + 1], x[n * 3 + 1]);
            atomicAdd(&xs[b * 3 + 2], x[n * 3 + 2]);
        }
    }
    {
        int n = base + ge;
        if (n < Nn) {
            const bf16* hr = hbuf + ((size_t)n << 6) + part * 16;
            *(bf16x8*)&inB[(((part * 2 + 0) * 64) + ge) << 3] = *(const bf16x8*)(hr);
            *(bf16x8*)&inB[(((part * 2 + 1) * 64) + ge) << 3] = *(const bf16x8*)(hr + 8);
        } else {
            bf16x8 zz = {(bf16)0.f, (bf16)0.f, (bf16)0.f, (bf16)0.f,
                         (bf16)0.f, (bf16)0.f, (bf16)0.f, (bf16)0.f};
            *(bf16x8*)&inB[(((part * 2 + 0) * 64) + ge) << 3] = zz;
            *(bf16x8*)&inB[(((part * 2 + 1) * 64) + ge) << 3] = zz;
        }
    }
    __syncthreads();
    f32x4 a1[4];
#pragma unroll
    for (int T = 0; T < 4; ++T) a1[T] = (f32x4){0.f, 0.f, 0.f, 0.f};
#pragma unroll
    for (int kc = 0; kc < 2; ++kc) {
        bf16x8 bfrag = *(const bf16x8*)&inB[(((kc * 4 + q) * 64) + w * 16 + nl) << 3];
#pragma unroll
        for (int T = 0; T < 4; ++T)
            a1[T] = __builtin_amdgcn_mfma_f32_16x16x32_bf16(w1f[kc][T], bfrag, a1[T], 0, 0, 0);
    }
    float pc = 0.f;
#pragma unroll
    for (int T = 0; T < 4; ++T) {
        const float4 bq = *(const float4*)&sb1[T * 16 + fq];
        const float4 cq = *(const float4*)&sw2[T * 16 + fq];
        pc += silu_f(a1[T][0] + bq.x) * cq.x;
        pc += silu_f(a1[T][1] + bq.y) * cq.y;
        pc += silu_f(a1[T][2] + bq.z) * cq.z;
        pc += silu_f(a1[T][3] + bq.w) * cq.w;
    }
    pc += __shfl_xor(pc, 16);
    pc += __shfl_xor(pc, 32);
    if (q == 0) {
        int n = base + w * 16 + nl;
        if (n < Nn) qout[n] = pc + qb2;
    }
}

__global__ void k_mu(const int* __restrict__ batch, const float* __restrict__ x,
                     const float* __restrict__ q, const float* __restrict__ cnt,
                     const float* __restrict__ xs, float* __restrict__ out) {
    int n = blockIdx.x * blockDim.x + threadIdx.x;
    if (n < Nn) {
        int b = batch[n];
        float cc = fmaxf(cnt[b], 1.f);
        float qn = q[n];
#pragma unroll
        for (int c = 0; c < 3; ++c) {
            float xr = x[n * 3 + c] - xs[b * 3 + c] / cc;
            atomicAdd(&out[b * 3 + c], qn * xr);
        }
    }
}

// ---------------- launch ----------------
extern "C" void kernel_launch(void* const* d_in, const int* in_sizes, int n_in,
                              void* d_out, int out_size, void* d_ws, size_t ws_size,
                              hipStream_t stream) {
    const int* z = (const int*)d_in[0];
    const float* pos = (const float*)d_in[1];
    const int* ei0 = (const int*)d_in[2];
    const int* ei1 = ei0 + Ee;
    const int* batch = (const int*)d_in[3];
    const float* emb = (const float*)d_in[4];
    const float* eW1 = (const float*)d_in[5];
    const float* eb1 = (const float*)d_in[6];
    const float* eW2 = (const float*)d_in[7];
    const float* eb2 = (const float*)d_in[8];
    const float* cW = (const float*)d_in[9];
    const float* cb = (const float*)d_in[10];
    const float* nW1 = (const float*)d_in[11];
    const float* nb1 = (const float*)d_in[12];
    const float* nW2 = (const float*)d_in[13];
    const float* nb2 = (const float*)d_in[14];
    const float* qW1 = (const float*)d_in[15];
    const float* qb1 = (const float*)d_in[16];
    const float* qW2 = (const float*)d_in[17];
    const float* qb2 = (const float*)d_in[18];

    char* ws = (char*)d_ws;
    size_t o = 0;
    auto alloc = [&](size_t bytes) {
        size_t r = o;
        o = (o + bytes + 255) & ~(size_t)255;
        return r;
    };
    float* h = (float*)(ws + alloc((size_t)Nn * 64 * 4));
    float* xp = (float*)(ws + alloc((size_t)Nn * 3 * 4));
    float* magg = (float*)(ws + alloc((size_t)Nn * 64 * 4));
    float* xacc = (float*)(ws + alloc((size_t)Nn * 3 * 4));
    size_t zero_span = (size_t)((char*)xacc - (char*)magg) + (size_t)Nn * 3 * 4;
    float* qv = (float*)(ws + alloc((size_t)Nn * 4));
    int* deg = (int*)(ws + alloc((size_t)Nn * 4));
    int* cur = (int*)(ws + alloc((size_t)Nn * 4));
    int* rows_s = (int*)(ws + alloc((size_t)Ee * 4));
    int* cols_s = (int*)(ws + alloc((size_t)Ee * 4));
    float* cnt = (float*)(ws + alloc((size_t)Bb * 4));
    float* xs = (float*)(ws + alloc((size_t)Bb * 3 * 4));
    bf16* hbm = (bf16*)(ws + alloc((size_t)Nn * 64 * 2));
    bf16* Pa = (bf16*)(ws + alloc((size_t)Nn * 64 * 2));
    bf16* Pb = (bf16*)(ws + alloc((size_t)Nn * 64 * 2));
    bf16* pw1 = (bf16*)(ws + alloc((size_t)4 * 8192 * 2));
    bf16* pw2 = (bf16*)(ws + alloc((size_t)4 * 4096 * 2));
    bf16* pn1 = (bf16*)(ws + alloc((size_t)4 * 8192 * 2));
    bf16* pn2 = (bf16*)(ws + alloc((size_t)4 * 4096 * 2));
    bf16* pq1 = (bf16*)(ws + alloc((size_t)4096 * 2));
    int* bsum = (int*)(ws + alloc((size_t)NB * 4));
    int* boff = (int*)(ws + alloc((size_t)NB * 4));

    hipMemsetAsync(deg, 0, (size_t)Nn * 4, stream);
    hipMemsetAsync(magg, 0, zero_span, stream);
    hipMemsetAsync(cnt, 0, (size_t)Bb * 4, stream);
    hipMemsetAsync(xs, 0, (size_t)Bb * 3 * 4, stream);
    hipMemsetAsync(d_out, 0, (size_t)out_size * 4, stream);

    hipMemcpyAsync(xp, pos, (size_t)Nn * 3 * 4, hipMemcpyDeviceToDevice, stream);
    k_setup<<<2048, 256, 0, stream>>>(h, hbm, z, emb, eW1, eW2, nW1, nW2, qW1,
                                      pw1, pw2, pn1, pn2, pq1, ei0, deg);
    k_scan1<<<NB, 256, 0, stream>>>(deg, bsum);
    k_scan2<<<1, 256, 0, stream>>>(bsum, boff);
    k_scan3<<<NB, 256, 0, stream>>>(deg, boff, cur, rows_s);
    k_scatter<<<(Ee + 255) / 256, 256, 0, stream>>>(ei0, ei1, cur, cols_s);

    k_proj<<<782, 256, 0, stream>>>(hbm, pw1, eb1, Pa, Pb);
    for (int l = 0; l < 4; ++l) {
        k_edge<<<6250, 256, 0, stream>>>(rows_s, cols_s, Pa, Pb, xp,
                                         pw2 + (size_t)l * 4096,
                                         eW1 + (size_t)l * 129 * 64,
                                         eb2 + l * 64,
                                         cW + l * 64, cb + l, magg, xacc);
        int nx = (l < 3) ? (l + 1) : 0;
        k_node<<<768, 256, 0, stream>>>(magg, xacc,
                                        pn1 + (size_t)l * 8192, pn2 + (size_t)l * 4096,
                                        nb1 + l * 64, nb2 + l * 64,
                                        h, hbm, xp,
                                        pw1 + (size_t)nx * 8192, eb1 + nx * 64,
                                        Pa, Pb, (l < 3) ? 1 : 0);
    }
    k_q<<<(Nn + 63) / 64, 256, 0, stream>>>(hbm, pq1, qb1, qW2, qb2, qv,
                                            batch, xp, cnt, xs);
    k_mu<<<(Nn + 255) / 256, 256, 0, stream>>>(batch, xp, qv, cnt, xs, (float*)d_out);
}